// Round 1
// baseline (537.803 us; speedup 1.0000x reference)
//
#include <hip/hip_runtime.h>
#include <hip/hip_bf16.h>

// STU forward: spectral conv (block-Toeplitz MFMA GEMM) + big contraction GEMM
// + Neumann-iterated output AR recurrence. All GEMMs bf16 MFMA 16x16x32, fp32 acc.
//
// Shapes: B=2, L=1024, D=512, K=16, k_u=3, k_y=2. Output (B,L,D) fp32.
// Workspace use ~141 MB.

using bf16 = __hip_bfloat16;
typedef __attribute__((ext_vector_type(8))) short bf16x8;
typedef __attribute__((ext_vector_type(4))) float f32x4;

#define B_   2
#define L_   1024
#define D_   512
#define K_   16
#define KT   17920      // 32*512 (phi) + 3*512 (M_u taps)
#define ROWS 2048       // B*L

__device__ __forceinline__ void gll16(const void* g, void* l) {
    __builtin_amdgcn_global_load_lds(
        (const __attribute__((address_space(1))) unsigned int*)g,
        (__attribute__((address_space(3))) unsigned int*)l, 16, 0, 0);
}

// ---------------- prep kernels ----------------

// u (B,L,D) fp32 -> uT (B,D,L) bf16 (tiled transpose)
__global__ void k_transpose_u(const float* __restrict__ u, bf16* __restrict__ uT) {
    __shared__ bf16 t[64][72];
    int lt = blockIdx.x * 64, dt = blockIdx.y * 64, b = blockIdx.z;
    int col = threadIdx.x & 63, r0 = (threadIdx.x >> 6) * 16;
    for (int i = 0; i < 16; ++i)
        t[r0 + i][col] = __float2bfloat16(u[((size_t)b * L_ + lt + r0 + i) * D_ + dt + col]);
    __syncthreads();
    for (int i = 0; i < 16; ++i)
        uT[((size_t)b * D_ + dt + r0 + i) * L_ + lt + col] = t[col][r0 + i];
}

// Toeplitz blocks: W[c][g][kb][i(128)][j(32)] = wtilde_c[g*128 + i - kb*32 - j]
// wtilde_c[x] = filters[x][c&15] * ((c>=16 && x odd) ? -1 : 1), 0 for x<0
__global__ void k_build_wtiled(const float* __restrict__ fil, bf16* __restrict__ W) {
    int tile = blockIdx.x;                 // 32*8*4 = 1024 tiles
    int kb = tile & 3, g = (tile >> 2) & 7, c = tile >> 5;
    int k = c & 15;
    for (int idx = threadIdx.x; idx < 4096; idx += blockDim.x) {
        int i = idx >> 5, j = idx & 31;
        int x = g * 128 + i - kb * 32 - j;
        float v = 0.f;
        if (x >= 0) {
            v = fil[x * K_ + k];
            if (c >= 16 && (x & 1)) v = -v;
        }
        W[(size_t)tile * 4096 + idx] = __float2bfloat16(v);
    }
}

// BT[o][c*512+d] = M_c[d][o] (tiled transpose), c<16: plus, else minus
__global__ void k_build_bt_phi(const float* __restrict__ Mp, const float* __restrict__ Mm,
                               bf16* __restrict__ BT) {
    __shared__ bf16 t[64][72];
    int dt = blockIdx.x * 64, ot = blockIdx.y * 64, c = blockIdx.z;
    const float* src = (c < 16) ? (Mp + (size_t)c * D_ * D_) : (Mm + (size_t)(c - 16) * D_ * D_);
    int col = threadIdx.x & 63, r0 = (threadIdx.x >> 6) * 16;
    for (int i = 0; i < 16; ++i)
        t[r0 + i][col] = __float2bfloat16(src[(size_t)(dt + r0 + i) * D_ + ot + col]);
    __syncthreads();
    for (int i = 0; i < 16; ++i)
        BT[(size_t)(ot + r0 + i) * KT + c * D_ + dt + col] = t[col][r0 + i];
}

// BT[o][16384 + t*512 + f] = M_u[o][t][f]  (M_u layout already matches)
__global__ void k_copy_bt_mu(const float* __restrict__ Mu, bf16* __restrict__ BT) {
    int idx = blockIdx.x * blockDim.x + threadIdx.x;
    if (idx >= 512 * 1536) return;
    int o = idx / 1536, tf = idx % 1536;
    BT[(size_t)o * KT + 16384 + tf] = __float2bfloat16(Mu[idx]);
}

// U_ext[r][16384 + t*512 + f] = u[b][l-t][f] (zero for l<t)
__global__ void k_build_ushift(const float* __restrict__ u, bf16* __restrict__ A) {
    int idx = blockIdx.x * blockDim.x + threadIdx.x;
    if (idx >= ROWS * 1536) return;
    int r = idx / 1536, tf = idx % 1536;
    int t = tf >> 9, f = tf & 511;
    int b = r >> 10, l = r & 1023;
    float v = (l >= t) ? u[((size_t)b * L_ + l - t) * D_ + f] : 0.f;
    A[(size_t)r * KT + 16384 + tf] = __float2bfloat16(v);
}

// M_y (D,2,D) fp32 -> bf16; native layout [d][j][f] is exactly NstackT[n=d][kk]
__global__ void k_cvt_my(const float* __restrict__ My, bf16* __restrict__ NT) {
    int idx = blockIdx.x * blockDim.x + threadIdx.x;
    if (idx < D_ * 1024) NT[idx] = __float2bfloat16(My[idx]);
}

// Ash[r][0:512]=y[r-1], [512:1024]=y[r-2] (bf16, zero at batch-local l<1/<2)
__global__ void k_build_ash(const float* __restrict__ y, bf16* __restrict__ A) {
    int idx = blockIdx.x * blockDim.x + threadIdx.x;
    if (idx >= ROWS * 1024) return;
    int r = idx >> 10, cc = idx & 1023;
    int l = r & 1023;
    float v;
    if (cc < 512) v = (l >= 1) ? y[(size_t)(r - 1) * D_ + cc] : 0.f;
    else          v = (l >= 2) ? y[(size_t)(r - 2) * D_ + (cc - 512)] : 0.f;
    A[idx] = __float2bfloat16(v);
}

__global__ void k_reduce_z(const float* __restrict__ p, float* __restrict__ z) {
    int idx = blockIdx.x * blockDim.x + threadIdx.x;
    if (idx >= ROWS * D_) return;
    float s = 0.f;
    for (int c = 0; c < 5; ++c) s += p[(size_t)c * ROWS * D_ + idx];
    z[idx] = s;
}

// ---------------- GEMM kernels ----------------
// 128x128 tile, 256 thr = 4 waves, each wave 64x64 = 4x4 MFMA 16x16x32 tiles.
// LDS: sA[128][32] (A[m][k]), sB[128][32] (B stored n-major: sB[n][k]).
// Frag layouts (verified m89/m91/m120): A[m=lane&15][k=(lane>>4)*8+j],
// B[k=(lane>>4)*8+j][n=lane&15], C/D[row=(lane>>4)*4+reg][col=lane&15].

// Generic: out[r][n] (+= addsrc) = sum_k A[r][k]*BT[n][k]; chunk = blockIdx.z
__global__ __launch_bounds__(256, 2) void gemm_k(
    const bf16* __restrict__ A, int lda,
    const bf16* __restrict__ BT, int ldb,
    const float* __restrict__ addsrc,
    float* __restrict__ out, int out_chunk_stride, int k_chunk)
{
    __shared__ bf16 sA[128 * 32];
    __shared__ bf16 sB[128 * 32];
    const int row0 = blockIdx.x * 128, col0 = blockIdx.y * 128;
    const int k0 = blockIdx.z * k_chunk;
    const int tid = threadIdx.x, lane = tid & 63, wave = tid >> 6;
    const int wm = (wave & 1) * 64, wn = (wave >> 1) * 64;
    const int ml = lane & 15, q = lane >> 4;
    const int srow = lane >> 2, scol = (lane & 3) * 8;
    f32x4 acc[4][4] = {};

    for (int k = k0; k < k0 + k_chunk; k += 32) {
        __syncthreads();
        #pragma unroll
        for (int repi = 0; repi < 2; ++repi) {
            int a = wave + repi * 4;   // 8 staging slots, 16 rows each
            gll16(A  + (size_t)(row0 + a * 16 + srow) * lda + k + scol, &sA[a * 512]);
            gll16(BT + (size_t)(col0 + a * 16 + srow) * ldb + k + scol, &sB[a * 512]);
        }
        __syncthreads();
        bf16x8 af[4], bfr[4];
        #pragma unroll
        for (int i = 0; i < 4; ++i)
            af[i] = *(const bf16x8*)&sA[(wm + i * 16 + ml) * 32 + q * 8];
        #pragma unroll
        for (int j = 0; j < 4; ++j)
            bfr[j] = *(const bf16x8*)&sB[(wn + j * 16 + ml) * 32 + q * 8];
        #pragma unroll
        for (int i = 0; i < 4; ++i)
            #pragma unroll
            for (int j = 0; j < 4; ++j)
                acc[i][j] = __builtin_amdgcn_mfma_f32_16x16x32_bf16(af[i], bfr[j], acc[i][j], 0, 0, 0);
    }
    float* o = out + (size_t)blockIdx.z * out_chunk_stride;
    #pragma unroll
    for (int i = 0; i < 4; ++i)
        #pragma unroll
        for (int j = 0; j < 4; ++j)
            #pragma unroll
            for (int reg = 0; reg < 4; ++reg) {
                int r = row0 + wm + i * 16 + q * 4 + reg;
                int cc = col0 + wn + j * 16 + ml;
                float v = acc[i][j][reg];
                if (addsrc) v += addsrc[(size_t)r * D_ + cc];
                o[(size_t)r * D_ + cc] = v;
            }
}

// Stage C: U[(b,l)][c*512+d] = sum_s wtilde_c[l-s] * u[b][s][d], triangular K-skip.
// grid (8 l-tiles, 4 d-tiles, 64 = c*2+b)
__global__ __launch_bounds__(256, 2) void gemm_toep(
    const bf16* __restrict__ W,    // [c][g][kb][128][32] pre-tiled Toeplitz blocks
    const bf16* __restrict__ uT,   // [b][512][1024]
    bf16* __restrict__ U)          // [2048][KT]
{
    __shared__ bf16 sA[128 * 32];
    __shared__ bf16 sB[128 * 32];
    const int lt = blockIdx.x;
    const int col0 = blockIdx.y * 128;
    const int c = blockIdx.z >> 1, b = blockIdx.z & 1;
    const int tid = threadIdx.x, lane = tid & 63, wave = tid >> 6;
    const int wm = (wave & 1) * 64, wn = (wave >> 1) * 64;
    const int ml = lane & 15, q = lane >> 4;
    const int srow = lane >> 2, scol = (lane & 3) * 8;
    f32x4 acc[4][4] = {};
    const int kend = (lt + 1) * 128;

    for (int k = 0; k < kend; k += 32) {
        int sb = k >> 7, g = lt - sb, kb = (k >> 5) & 3;
        const bf16* wt = W + (((size_t)(c * 8 + g) * 4 + kb) * 4096);
        __syncthreads();
        #pragma unroll
        for (int repi = 0; repi < 2; ++repi) {
            int a = wave + repi * 4;
            gll16(wt + a * 512 + lane * 8, &sA[a * 512]);   // contiguous pre-tiled A
            gll16(uT + ((size_t)b * D_ + col0 + a * 16 + srow) * L_ + k + scol, &sB[a * 512]);
        }
        __syncthreads();
        bf16x8 af[4], bfr[4];
        #pragma unroll
        for (int i = 0; i < 4; ++i)
            af[i] = *(const bf16x8*)&sA[(wm + i * 16 + ml) * 32 + q * 8];
        #pragma unroll
        for (int j = 0; j < 4; ++j)
            bfr[j] = *(const bf16x8*)&sB[(wn + j * 16 + ml) * 32 + q * 8];
        #pragma unroll
        for (int i = 0; i < 4; ++i)
            #pragma unroll
            for (int j = 0; j < 4; ++j)
                acc[i][j] = __builtin_amdgcn_mfma_f32_16x16x32_bf16(af[i], bfr[j], acc[i][j], 0, 0, 0);
    }
    #pragma unroll
    for (int i = 0; i < 4; ++i)
        #pragma unroll
        for (int j = 0; j < 4; ++j)
            #pragma unroll
            for (int reg = 0; reg < 4; ++reg) {
                int l = lt * 128 + wm + i * 16 + q * 4 + reg;
                int d = col0 + wn + j * 16 + ml;
                U[(size_t)(b * L_ + l) * KT + c * D_ + d] = __float2bfloat16(acc[i][j][reg]);
            }
}

// ---------------- launch ----------------
extern "C" void kernel_launch(void* const* d_in, const int* in_sizes, int n_in,
                              void* d_out, int out_size, void* d_ws, size_t ws_size,
                              hipStream_t stream) {
    const float* u   = (const float*)d_in[0];
    const float* fil = (const float*)d_in[1];
    const float* Mu  = (const float*)d_in[2];
    const float* My  = (const float*)d_in[3];
    const float* Mp  = (const float*)d_in[4];
    const float* Mm  = (const float*)d_in[5];
    float* out = (float*)d_out;

    char* ws = (char*)d_ws;
    size_t off = 0;
    auto alloc = [&](size_t bytes) { void* p = ws + off; off = (off + bytes + 255) & ~(size_t)255; return p; };
    bf16*  U    = (bf16*) alloc((size_t)ROWS * KT * 2);        // 73.4 MB
    bf16*  BT   = (bf16*) alloc((size_t)512 * KT * 2);         // 18.4 MB
    bf16*  W    = (bf16*) alloc((size_t)1024 * 4096 * 2);      //  8.4 MB
    bf16*  uT   = (bf16*) alloc((size_t)B_ * D_ * L_ * 2);     //  2   MB
    bf16*  NT   = (bf16*) alloc((size_t)D_ * 1024 * 2);        //  1   MB
    float* part = (float*)alloc((size_t)5 * ROWS * D_ * 4);    // 21   MB
    float* z    = (float*)alloc((size_t)ROWS * D_ * 4);        //  4.2 MB
    float* y0   = (float*)alloc((size_t)ROWS * D_ * 4);
    float* y1   = (float*)alloc((size_t)ROWS * D_ * 4);
    bf16*  Ash  = (bf16*) alloc((size_t)ROWS * 1024 * 2);      //  4.2 MB

    // preps
    k_transpose_u <<<dim3(16, 8, 2),  256, 0, stream>>>(u, uT);
    k_build_wtiled<<<1024,            256, 0, stream>>>(fil, W);
    k_build_bt_phi<<<dim3(8, 8, 32),  256, 0, stream>>>(Mp, Mm, BT);
    k_copy_bt_mu  <<<(512 * 1536 + 255) / 256, 256, 0, stream>>>(Mu, BT);
    k_build_ushift<<<(ROWS * 1536 + 255) / 256, 256, 0, stream>>>(u, U);
    k_cvt_my      <<<(D_ * 1024 + 255) / 256,   256, 0, stream>>>(My, NT);

    // Stage C: spectral convolution (block-Toeplitz GEMM), writes U cols [0,16384)
    gemm_toep<<<dim3(8, 4, 64), 256, 0, stream>>>(W, uT, U);

    // Stage D: z = U_ext @ B  (split-K = 5, deterministic partials)
    gemm_k<<<dim3(16, 4, 5), 256, 0, stream>>>(U, KT, BT, KT, nullptr, part, ROWS * D_, 3584);
    k_reduce_z<<<(ROWS * D_ + 255) / 256, 256, 0, stream>>>(part, z);

    // Stage R: 8 Neumann iterations of y = z + shift1(y)N1 + shift2(y)N2
    const float* cur = z;
    for (int it = 0; it < 8; ++it) {
        k_build_ash<<<(ROWS * 1024 + 255) / 256, 256, 0, stream>>>(cur, Ash);
        float* nxt = (it == 7) ? out : ((it & 1) ? y1 : y0);
        gemm_k<<<dim3(16, 4, 1), 256, 0, stream>>>(Ash, 1024, NT, 1024, z, nxt, 0, 1024);
        cur = nxt;
    }
}

// Round 2
// 420.053 us; speedup vs baseline: 1.2803x; 1.2803x over previous
//
#include <hip/hip_runtime.h>
#include <hip/hip_bf16.h>

// STU forward: spectral conv (block-Toeplitz MFMA GEMM) + big contraction GEMM
// + explicit-tap AR solve (y = sum_s z_{t-s} Phi_s, Phi via 7 tiny GEMMs).
// All GEMMs bf16 MFMA 16x16x32, fp32 acc. Split-K accumulates via fp32 atomicAdd.
// LDS column-group XOR swizzle (pg = q ^ ((row>>1)&3)) applied at the
// global_load_lds source side -> 2-way (free) bank access on ds_read_b128.
//
// Shapes: B=2, L=1024, D=512, K=16, k_u=3, k_y=2. Output (B,L,D) fp32.
// Workspace ~119 MB (ZT overlaps dead W/uT region).

using bf16 = __hip_bfloat16;
typedef __attribute__((ext_vector_type(8))) short bf16x8;
typedef __attribute__((ext_vector_type(4))) float f32x4;

#define B_   2
#define L_   1024
#define D_   512
#define K_   16
#define KT   17920      // 32*512 (phi) + 3*512 (M_u taps)
#define ROWS 2048       // B*L
#define NTAP 8          // AR taps s=1..8 (s=0 identity handled in fp32)
#define PBLD 4608       // PB row stride: 9 slots (s=0..8) * 512
#define ZTLD 4096       // ZT row stride: 8 taps * 512

__device__ __forceinline__ void gll16(const void* g, void* l) {
    __builtin_amdgcn_global_load_lds(
        (const __attribute__((address_space(1))) unsigned int*)g,
        (__attribute__((address_space(3))) unsigned int*)l, 16, 0, 0);
}

// ---------------- prep kernels ----------------

// u (B,L,D) fp32 -> uT (B,D,L) bf16 (tiled transpose)
__global__ void k_transpose_u(const float* __restrict__ u, bf16* __restrict__ uT) {
    __shared__ bf16 t[64][72];
    int lt = blockIdx.x * 64, dt = blockIdx.y * 64, b = blockIdx.z;
    int col = threadIdx.x & 63, r0 = (threadIdx.x >> 6) * 16;
    for (int i = 0; i < 16; ++i)
        t[r0 + i][col] = __float2bfloat16(u[((size_t)b * L_ + lt + r0 + i) * D_ + dt + col]);
    __syncthreads();
    for (int i = 0; i < 16; ++i)
        uT[((size_t)b * D_ + dt + r0 + i) * L_ + lt + col] = t[col][r0 + i];
}

// Toeplitz blocks, PRE-SWIZZLED: physical (i, jp) holds logical col
// j = (pgp ^ ((i>>1)&3))*8 + (jp&7); value = wtilde_c[g*128 + i - kb*32 - j]
__global__ void k_build_wtiled(const float* __restrict__ fil, bf16* __restrict__ W) {
    int tile = blockIdx.x;                 // 32*8*4 = 1024 tiles
    int kb = tile & 3, g = (tile >> 2) & 7, c = tile >> 5;
    int k = c & 15;
    for (int idx = threadIdx.x; idx < 4096; idx += blockDim.x) {
        int i = idx >> 5, jp = idx & 31;
        int j = ((jp >> 3) ^ ((i >> 1) & 3)) * 8 + (jp & 7);
        int x = g * 128 + i - kb * 32 - j;
        float v = 0.f;
        if (x >= 0) {
            v = fil[x * K_ + k];
            if (c >= 16 && (x & 1)) v = -v;
        }
        W[(size_t)tile * 4096 + idx] = __float2bfloat16(v);
    }
}

// BT[o][c*512+d] = M_c[d][o] (tiled transpose), c<16: plus, else minus
__global__ void k_build_bt_phi(const float* __restrict__ Mp, const float* __restrict__ Mm,
                               bf16* __restrict__ BT) {
    __shared__ bf16 t[64][72];
    int dt = blockIdx.x * 64, ot = blockIdx.y * 64, c = blockIdx.z;
    const float* src = (c < 16) ? (Mp + (size_t)c * D_ * D_) : (Mm + (size_t)(c - 16) * D_ * D_);
    int col = threadIdx.x & 63, r0 = (threadIdx.x >> 6) * 16;
    for (int i = 0; i < 16; ++i)
        t[r0 + i][col] = __float2bfloat16(src[(size_t)(dt + r0 + i) * D_ + ot + col]);
    __syncthreads();
    for (int i = 0; i < 16; ++i)
        BT[(size_t)(ot + r0 + i) * KT + c * D_ + dt + col] = t[col][r0 + i];
}

// BT[o][16384 + t*512 + f] = M_u[o][t][f]
__global__ void k_copy_bt_mu(const float* __restrict__ Mu, bf16* __restrict__ BT) {
    int idx = blockIdx.x * blockDim.x + threadIdx.x;
    if (idx >= 512 * 1536) return;
    int o = idx / 1536, tf = idx % 1536;
    BT[(size_t)o * KT + 16384 + tf] = __float2bfloat16(Mu[idx]);
}

// U_ext[r][16384 + t*512 + f] = u[b][l-t][f]
__global__ void k_build_ushift(const float* __restrict__ u, bf16* __restrict__ A) {
    int idx = blockIdx.x * blockDim.x + threadIdx.x;
    if (idx >= ROWS * 1536) return;
    int r = idx / 1536, tf = idx % 1536;
    int t = tf >> 9, f = tf & 511;
    int b = r >> 10, l = r & 1023;
    float v = (l >= t) ? u[((size_t)b * L_ + l - t) * D_ + f] : 0.f;
    A[(size_t)r * KT + 16384 + tf] = __float2bfloat16(v);
}

// PB[n][c]: c<512 -> P0 = I; c in [512,1024) -> P1[n][f] = M_y[n][0][f]
__global__ void k_init_pb(const float* __restrict__ My, bf16* __restrict__ PB) {
    int idx = blockIdx.x * blockDim.x + threadIdx.x;
    if (idx >= 512 * 1024) return;
    int n = idx >> 10, c = idx & 1023;
    float v = (c < 512) ? ((n == c) ? 1.f : 0.f) : My[(size_t)n * 1024 + (c - 512)];
    PB[(size_t)n * PBLD + c] = __float2bfloat16(v);
}

// BT2[f][h*512+d] = M_y[d][1-h][f]  (h=0: N2, h=1: N1) -- tiled transpose
__global__ void k_build_bt2(const float* __restrict__ My, bf16* __restrict__ BT2) {
    __shared__ bf16 t[64][72];
    int dt = blockIdx.x * 64, ft = blockIdx.y * 64, h = blockIdx.z;
    int col = threadIdx.x & 63, r0 = (threadIdx.x >> 6) * 16;
    for (int i = 0; i < 16; ++i)
        t[r0 + i][col] = __float2bfloat16(My[(size_t)(dt + r0 + i) * 1024 + (1 - h) * 512 + ft + col]);
    __syncthreads();
    for (int i = 0; i < 16; ++i)
        BT2[(size_t)(ft + r0 + i) * 1024 + h * 512 + dt + col] = t[col][r0 + i];
}

// z (fp32, final) -> shifted bf16 taps: ZT[r'][(s-1)*512+f] = z[r'-s][f] (0 if l'<s)
__global__ void k_build_ztaps(const float* __restrict__ z, bf16* __restrict__ ZT) {
    int idx = blockIdx.x * blockDim.x + threadIdx.x;
    if (idx >= ROWS * D_) return;
    int r = idx >> 9, f = idx & 511;
    int l = r & 1023;
    bf16 zb = __float2bfloat16(z[idx]);
    #pragma unroll
    for (int s = 1; s <= NTAP; ++s)
        if (l + s < 1024) ZT[(size_t)(r + s) * ZTLD + (s - 1) * 512 + f] = zb;
    for (int s = l + 1; s <= NTAP; ++s)
        ZT[(size_t)r * ZTLD + (s - 1) * 512 + f] = __float2bfloat16(0.f);
}

// ---------------- GEMM kernels ----------------
// 128x128 tile, 256 thr = 4 waves, each wave 64x64 = 4x4 MFMA 16x16x32 tiles.
// LDS sA/sB: row-major 128x32 with column-group swizzle pg = q ^ ((row>>1)&3).
// Staging: lane (srow=lane>>2, pg=lane&3) fetches logical group pg^((srow>>1)&3).

// out[r][n] += sum_k A[r][k]*BT[n][k]  (fp32 atomicAdd; out col dim = 512)
__global__ __launch_bounds__(256, 2) void gemm_k(
    const bf16* __restrict__ A, int lda,
    const bf16* __restrict__ BT, int ldb,
    float* __restrict__ out, int k_chunk)
{
    __shared__ bf16 sA[128 * 32];
    __shared__ bf16 sB[128 * 32];
    const int row0 = blockIdx.x * 128, col0 = blockIdx.y * 128;
    const int k0 = blockIdx.z * k_chunk;
    const int tid = threadIdx.x, lane = tid & 63, wave = tid >> 6;
    const int wm = (wave & 1) * 64, wn = (wave >> 1) * 64;
    const int ml = lane & 15, q = lane >> 4;
    const int srow = lane >> 2, scol = (((lane & 3) ^ ((srow >> 1) & 3))) * 8;
    const int swz = ((ml >> 1) & 3);
    f32x4 acc[4][4] = {};

    for (int k = k0; k < k0 + k_chunk; k += 32) {
        __syncthreads();
        #pragma unroll
        for (int repi = 0; repi < 2; ++repi) {
            int a = wave + repi * 4;
            gll16(A  + (size_t)(row0 + a * 16 + srow) * lda + k + scol, &sA[a * 512]);
            gll16(BT + (size_t)(col0 + a * 16 + srow) * ldb + k + scol, &sB[a * 512]);
        }
        __syncthreads();
        bf16x8 af[4], bfr[4];
        #pragma unroll
        for (int i = 0; i < 4; ++i)
            af[i] = *(const bf16x8*)&sA[(wm + i * 16 + ml) * 32 + (q ^ swz) * 8];
        #pragma unroll
        for (int j = 0; j < 4; ++j)
            bfr[j] = *(const bf16x8*)&sB[(wn + j * 16 + ml) * 32 + (q ^ swz) * 8];
        #pragma unroll
        for (int i = 0; i < 4; ++i)
            #pragma unroll
            for (int j = 0; j < 4; ++j)
                acc[i][j] = __builtin_amdgcn_mfma_f32_16x16x32_bf16(af[i], bfr[j], acc[i][j], 0, 0, 0);
    }
    #pragma unroll
    for (int i = 0; i < 4; ++i)
        #pragma unroll
        for (int j = 0; j < 4; ++j)
            #pragma unroll
            for (int reg = 0; reg < 4; ++reg) {
                int r = row0 + wm + i * 16 + q * 4 + reg;
                int cc = col0 + wn + j * 16 + ml;
                atomicAdd(&out[(size_t)r * D_ + cc], acc[i][j][reg]);
            }
}

// Phi-chain step: out_bf16[n][f] = sum_k A[n][k]*BT[f][k], 512x512, K=1024
__global__ __launch_bounds__(256, 2) void gemm_phi(
    const bf16* __restrict__ A, int lda,
    const bf16* __restrict__ BT, int ldb,
    bf16* __restrict__ out, int ldo)
{
    __shared__ bf16 sA[128 * 32];
    __shared__ bf16 sB[128 * 32];
    const int row0 = blockIdx.x * 128, col0 = blockIdx.y * 128;
    const int tid = threadIdx.x, lane = tid & 63, wave = tid >> 6;
    const int wm = (wave & 1) * 64, wn = (wave >> 1) * 64;
    const int ml = lane & 15, q = lane >> 4;
    const int srow = lane >> 2, scol = (((lane & 3) ^ ((srow >> 1) & 3))) * 8;
    const int swz = ((ml >> 1) & 3);
    f32x4 acc[4][4] = {};

    for (int k = 0; k < 1024; k += 32) {
        __syncthreads();
        #pragma unroll
        for (int repi = 0; repi < 2; ++repi) {
            int a = wave + repi * 4;
            gll16(A  + (size_t)(row0 + a * 16 + srow) * lda + k + scol, &sA[a * 512]);
            gll16(BT + (size_t)(col0 + a * 16 + srow) * ldb + k + scol, &sB[a * 512]);
        }
        __syncthreads();
        bf16x8 af[4], bfr[4];
        #pragma unroll
        for (int i = 0; i < 4; ++i)
            af[i] = *(const bf16x8*)&sA[(wm + i * 16 + ml) * 32 + (q ^ swz) * 8];
        #pragma unroll
        for (int j = 0; j < 4; ++j)
            bfr[j] = *(const bf16x8*)&sB[(wn + j * 16 + ml) * 32 + (q ^ swz) * 8];
        #pragma unroll
        for (int i = 0; i < 4; ++i)
            #pragma unroll
            for (int j = 0; j < 4; ++j)
                acc[i][j] = __builtin_amdgcn_mfma_f32_16x16x32_bf16(af[i], bfr[j], acc[i][j], 0, 0, 0);
    }
    #pragma unroll
    for (int i = 0; i < 4; ++i)
        #pragma unroll
        for (int j = 0; j < 4; ++j)
            #pragma unroll
            for (int reg = 0; reg < 4; ++reg) {
                int r = row0 + wm + i * 16 + q * 4 + reg;
                int cc = col0 + wn + j * 16 + ml;
                out[(size_t)r * ldo + cc] = __float2bfloat16(acc[i][j][reg]);
            }
}

// Stage C: U[(b,l)][c*512+d] = sum_s wtilde_c[l-s]*u[b][s][d], triangular K-skip.
__global__ __launch_bounds__(256, 2) void gemm_toep(
    const bf16* __restrict__ W,    // pre-tiled + pre-swizzled Toeplitz blocks
    const bf16* __restrict__ uT,   // [b][512][1024]
    bf16* __restrict__ U)          // [2048][KT]
{
    __shared__ bf16 sA[128 * 32];
    __shared__ bf16 sB[128 * 32];
    const int lt = blockIdx.x;
    const int col0 = blockIdx.y * 128;
    const int c = blockIdx.z >> 1, b = blockIdx.z & 1;
    const int tid = threadIdx.x, lane = tid & 63, wave = tid >> 6;
    const int wm = (wave & 1) * 64, wn = (wave >> 1) * 64;
    const int ml = lane & 15, q = lane >> 4;
    const int srow = lane >> 2, scol = (((lane & 3) ^ ((srow >> 1) & 3))) * 8;
    const int swz = ((ml >> 1) & 3);
    f32x4 acc[4][4] = {};
    const int kend = (lt + 1) * 128;

    for (int k = 0; k < kend; k += 32) {
        int sb = k >> 7, g = lt - sb, kb = (k >> 5) & 3;
        const bf16* wt = W + (((size_t)(c * 8 + g) * 4 + kb) * 4096);
        __syncthreads();
        #pragma unroll
        for (int repi = 0; repi < 2; ++repi) {
            int a = wave + repi * 4;
            gll16(wt + a * 512 + lane * 8, &sA[a * 512]);   // pre-swizzled contiguous
            gll16(uT + ((size_t)b * D_ + col0 + a * 16 + srow) * L_ + k + scol, &sB[a * 512]);
        }
        __syncthreads();
        bf16x8 af[4], bfr[4];
        #pragma unroll
        for (int i = 0; i < 4; ++i)
            af[i] = *(const bf16x8*)&sA[(wm + i * 16 + ml) * 32 + (q ^ swz) * 8];
        #pragma unroll
        for (int j = 0; j < 4; ++j)
            bfr[j] = *(const bf16x8*)&sB[(wn + j * 16 + ml) * 32 + (q ^ swz) * 8];
        #pragma unroll
        for (int i = 0; i < 4; ++i)
            #pragma unroll
            for (int j = 0; j < 4; ++j)
                acc[i][j] = __builtin_amdgcn_mfma_f32_16x16x32_bf16(af[i], bfr[j], acc[i][j], 0, 0, 0);
    }
    #pragma unroll
    for (int i = 0; i < 4; ++i)
        #pragma unroll
        for (int j = 0; j < 4; ++j)
            #pragma unroll
            for (int reg = 0; reg < 4; ++reg) {
                int l = lt * 128 + wm + i * 16 + q * 4 + reg;
                int d = col0 + wn + j * 16 + ml;
                U[(size_t)(b * L_ + l) * KT + c * D_ + d] = __float2bfloat16(acc[i][j][reg]);
            }
}

// ---------------- launch ----------------
extern "C" void kernel_launch(void* const* d_in, const int* in_sizes, int n_in,
                              void* d_out, int out_size, void* d_ws, size_t ws_size,
                              hipStream_t stream) {
    const float* u   = (const float*)d_in[0];
    const float* fil = (const float*)d_in[1];
    const float* Mu  = (const float*)d_in[2];
    const float* My  = (const float*)d_in[3];
    const float* Mp  = (const float*)d_in[4];
    const float* Mm  = (const float*)d_in[5];
    float* out = (float*)d_out;

    char* ws = (char*)d_ws;
    size_t off = 0;
    auto alloc = [&](size_t bytes) { void* p = ws + off; off = (off + bytes + 255) & ~(size_t)255; return p; };
    bf16*  U    = (bf16*) alloc((size_t)ROWS * KT * 2);        // 73.4 MB
    bf16*  BT   = (bf16*) alloc((size_t)512 * KT * 2);         // 18.4 MB
    bf16*  PB   = (bf16*) alloc((size_t)512 * PBLD * 2);       //  4.7 MB
    bf16*  BT2  = (bf16*) alloc((size_t)512 * 1024 * 2);       //  1.0 MB
    float* z    = (float*)alloc((size_t)ROWS * D_ * 4);        //  4.2 MB
    // shared region: {W + uT} live only through gemm_toep; ZT written after
    char*  shared = (char*)alloc((size_t)ROWS * ZTLD * 2);     // 16.8 MB
    bf16*  W    = (bf16*)shared;                               //  8.4 MB
    bf16*  uT   = (bf16*)(shared + (size_t)1024 * 4096 * 2);   //  2.0 MB
    bf16*  ZT   = (bf16*)shared;

    // preps
    k_transpose_u <<<dim3(16, 8, 2),  256, 0, stream>>>(u, uT);
    k_build_wtiled<<<1024,            256, 0, stream>>>(fil, W);
    k_build_bt_phi<<<dim3(8, 8, 32),  256, 0, stream>>>(Mp, Mm, BT);
    k_copy_bt_mu  <<<(512 * 1536 + 255) / 256, 256, 0, stream>>>(Mu, BT);
    k_build_ushift<<<(ROWS * 1536 + 255) / 256, 256, 0, stream>>>(u, U);
    k_init_pb     <<<(512 * 1024 + 255) / 256,  256, 0, stream>>>(My, PB);
    k_build_bt2   <<<dim3(8, 8, 2),   256, 0, stream>>>(My, BT2);

    // Phi chain: P_s = P_{s-1} N1^T + P_{s-2} N2^T, s=2..8 (tiny GEMMs)
    for (int s = 2; s <= NTAP; ++s)
        gemm_phi<<<dim3(4, 4), 256, 0, stream>>>(PB + (size_t)(s - 2) * 512, PBLD,
                                                 BT2, 1024,
                                                 PB + (size_t)s * 512, PBLD);

    // Stage C: spectral convolution (block-Toeplitz GEMM), U cols [0,16384)
    gemm_toep<<<dim3(8, 4, 64), 256, 0, stream>>>(W, uT, U);

    // Stage D: z = U_ext @ B, split-K = 8, atomic fp32 accumulate
    hipMemsetAsync(z, 0, (size_t)ROWS * D_ * 4, stream);
    gemm_k<<<dim3(16, 4, 8), 256, 0, stream>>>(U, KT, BT, KT, z, 2240);

    // Stage R: y = z + sum_{s=1..8} shift(z,s) Phi_s  (one split-K GEMM)
    k_build_ztaps<<<(ROWS * D_ + 255) / 256, 256, 0, stream>>>(z, ZT);
    hipMemcpyAsync(out, z, (size_t)ROWS * D_ * 4, hipMemcpyDeviceToDevice, stream);
    gemm_k<<<dim3(16, 4, 4), 256, 0, stream>>>(ZT, ZTLD, PB + 512, PBLD, out, 1024);
}

// Round 3
// 392.874 us; speedup vs baseline: 1.3689x; 1.0692x over previous
//
#include <hip/hip_runtime.h>
#include <hip/hip_bf16.h>

// STU forward: spectral conv (block-Toeplitz MFMA GEMM) + big contraction GEMM
// + explicit-tap AR solve (y = sum_{s=0..6} z_{t-s} Phi_s, Phi via 5 tiny GEMMs).
// All GEMMs bf16 MFMA 16x16x32, fp32 acc. Split-K accumulates via fp32 atomicAdd.
// LDS column-group XOR swizzle (pg = q ^ ((row>>1)&3)) -> 0 bank conflicts (R2).
// R3: Stage D split-K 16 (4 blocks/CU), NTAP 6, launches 20 -> 10.
//
// Shapes: B=2, L=1024, D=512, K=16, k_u=3, k_y=2. Output (B,L,D) fp32.

using bf16 = __hip_bfloat16;
typedef __attribute__((ext_vector_type(8))) short bf16x8;
typedef __attribute__((ext_vector_type(4))) float f32x4;

#define B_   2
#define L_   1024
#define D_   512
#define K_   16
#define KT   17920      // 32*512 (phi) + 3*512 (M_u taps)
#define ROWS 2048       // B*L
#define NTAP 6          // AR taps s=1..6 (s=0 identity handled in fp32)
#define PBLD 3584       // PB row stride: 7 slots (s=0..6) * 512
#define ZTLD 3072       // ZT row stride: 6 taps * 512

__device__ __forceinline__ void gll16(const void* g, void* l) {
    __builtin_amdgcn_global_load_lds(
        (const __attribute__((address_space(1))) unsigned int*)g,
        (__attribute__((address_space(3))) unsigned int*)l, 16, 0, 0);
}

// ---------------- prep: merged elementwise kernel ----------------
// block ranges: [0,12288) ushift | [12288,15360) bt_mu | [15360,17408) init_pb
//               [17408,18432) wtiled | [18432,22528) zero z
__global__ void prep_ew(const float* __restrict__ u, const float* __restrict__ fil,
                        const float* __restrict__ Mu, const float* __restrict__ My,
                        bf16* __restrict__ U, bf16* __restrict__ BT,
                        bf16* __restrict__ PB, bf16* __restrict__ W,
                        float* __restrict__ z) {
    int bid = blockIdx.x, tid = threadIdx.x;
    if (bid < 12288) {                       // U_ext[r][16384+t*512+f] = u[b][l-t][f]
        int idx = bid * 256 + tid;
        int r = idx / 1536, tf = idx % 1536;
        int t = tf >> 9, f = tf & 511;
        int b = r >> 10, l = r & 1023;
        float v = (l >= t) ? u[((size_t)b * L_ + l - t) * D_ + f] : 0.f;
        U[(size_t)r * KT + 16384 + tf] = __float2bfloat16(v);
    } else if (bid < 15360) {                // BT[o][16384+tf] = M_u[o][t][f]
        int idx = (bid - 12288) * 256 + tid;
        int o = idx / 1536, tf = idx % 1536;
        BT[(size_t)o * KT + 16384 + tf] = __float2bfloat16(Mu[idx]);
    } else if (bid < 17408) {                // PB: P0 = I, P1 = M_y[:,0,:]
        int idx = (bid - 15360) * 256 + tid;
        int n = idx >> 10, c = idx & 1023;
        float v = (c < 512) ? ((n == c) ? 1.f : 0.f) : My[(size_t)n * 1024 + (c - 512)];
        PB[(size_t)n * PBLD + c] = __float2bfloat16(v);
    } else if (bid < 18432) {                // Toeplitz blocks, pre-swizzled
        int tile = bid - 17408;              // 32*8*4 tiles
        int kb = tile & 3, g = (tile >> 2) & 7, c = tile >> 5;
        int k = c & 15;
        for (int idx = tid; idx < 4096; idx += 256) {
            int i = idx >> 5, jp = idx & 31;
            int j = ((jp >> 3) ^ ((i >> 1) & 3)) * 8 + (jp & 7);
            int x = g * 128 + i - kb * 32 - j;
            float v = 0.f;
            if (x >= 0) {
                v = fil[x * K_ + k];
                if (c >= 16 && (x & 1)) v = -v;
            }
            W[(size_t)tile * 4096 + idx] = __float2bfloat16(v);
        }
    } else {                                 // zero z for atomic accumulation
        int idx = (bid - 18432) * 256 + tid;
        z[idx] = 0.f;
    }
}

// ---------------- prep: merged transpose kernel ----------------
// grid (8,8,35): z<32 bt_phi | z=32,33 bt2 | z=34 transpose_u (loops b,lt)
__global__ void prep_tr(const float* __restrict__ Mp, const float* __restrict__ Mm,
                        const float* __restrict__ My, const float* __restrict__ u,
                        bf16* __restrict__ BT, bf16* __restrict__ BT2,
                        bf16* __restrict__ uT) {
    __shared__ bf16 t[64][72];
    int zb = blockIdx.z;
    int col = threadIdx.x & 63, r0 = (threadIdx.x >> 6) * 16;
    if (zb < 32) {                           // BT[o][c*512+d] = M_c[d][o]
        int dt = blockIdx.x * 64, ot = blockIdx.y * 64, c = zb;
        const float* src = (c < 16) ? (Mp + (size_t)c * D_ * D_)
                                    : (Mm + (size_t)(c - 16) * D_ * D_);
        for (int i = 0; i < 16; ++i)
            t[r0 + i][col] = __float2bfloat16(src[(size_t)(dt + r0 + i) * D_ + ot + col]);
        __syncthreads();
        for (int i = 0; i < 16; ++i)
            BT[(size_t)(ot + r0 + i) * KT + c * D_ + dt + col] = t[col][r0 + i];
    } else if (zb < 34) {                    // BT2[f][h*512+d] = M_y[d][1-h][f]
        int h = zb - 32;
        int dt = blockIdx.x * 64, ft = blockIdx.y * 64;
        for (int i = 0; i < 16; ++i)
            t[r0 + i][col] = __float2bfloat16(My[(size_t)(dt + r0 + i) * 1024 + (1 - h) * 512 + ft + col]);
        __syncthreads();
        for (int i = 0; i < 16; ++i)
            BT2[(size_t)(ft + r0 + i) * 1024 + h * 512 + dt + col] = t[col][r0 + i];
    } else {                                 // uT[b][d][l] = u[b][l][d]
        for (int it = 0; it < 4; ++it) {
            int b = it >> 1;
            int lt = (blockIdx.x + 8 * (it & 1)) * 64, dt = blockIdx.y * 64;
            __syncthreads();
            for (int i = 0; i < 16; ++i)
                t[r0 + i][col] = __float2bfloat16(u[((size_t)b * L_ + lt + r0 + i) * D_ + dt + col]);
            __syncthreads();
            for (int i = 0; i < 16; ++i)
                uT[((size_t)b * D_ + dt + r0 + i) * L_ + lt + col] = t[col][r0 + i];
        }
    }
}

// z (fp32, final) -> out copy + shifted bf16 taps
__global__ void k_build_ztaps(const float* __restrict__ z, bf16* __restrict__ ZT,
                              float* __restrict__ out) {
    int idx = blockIdx.x * blockDim.x + threadIdx.x;
    if (idx >= ROWS * D_) return;
    int r = idx >> 9, f = idx & 511;
    int l = r & 1023;
    float zv = z[idx];
    out[idx] = zv;
    bf16 zb = __float2bfloat16(zv);
    #pragma unroll
    for (int s = 1; s <= NTAP; ++s)
        if (l + s < 1024) ZT[(size_t)(r + s) * ZTLD + (s - 1) * 512 + f] = zb;
    for (int s = l + 1; s <= NTAP; ++s)
        ZT[(size_t)r * ZTLD + (s - 1) * 512 + f] = __float2bfloat16(0.f);
}

// ---------------- GEMM kernels ----------------
// 128x128 tile, 256 thr = 4 waves, each wave 64x64 = 4x4 MFMA 16x16x32 tiles.
// LDS sA/sB: row-major 128x32 with column-group swizzle pg = q ^ ((row>>1)&3).

// out[r][n] += sum_k A[r][k]*BT[n][k]  (fp32 atomicAdd; out col dim = 512)
__global__ __launch_bounds__(256, 2) void gemm_k(
    const bf16* __restrict__ A, int lda,
    const bf16* __restrict__ BT, int ldb,
    float* __restrict__ out, int k_chunk)
{
    __shared__ bf16 sA[128 * 32];
    __shared__ bf16 sB[128 * 32];
    const int row0 = blockIdx.x * 128, col0 = blockIdx.y * 128;
    const int k0 = blockIdx.z * k_chunk;
    const int tid = threadIdx.x, lane = tid & 63, wave = tid >> 6;
    const int wm = (wave & 1) * 64, wn = (wave >> 1) * 64;
    const int ml = lane & 15, q = lane >> 4;
    const int srow = lane >> 2, scol = (((lane & 3) ^ ((srow >> 1) & 3))) * 8;
    const int swz = ((ml >> 1) & 3);
    f32x4 acc[4][4] = {};

    for (int k = k0; k < k0 + k_chunk; k += 32) {
        __syncthreads();
        #pragma unroll
        for (int repi = 0; repi < 2; ++repi) {
            int a = wave + repi * 4;
            gll16(A  + (size_t)(row0 + a * 16 + srow) * lda + k + scol, &sA[a * 512]);
            gll16(BT + (size_t)(col0 + a * 16 + srow) * ldb + k + scol, &sB[a * 512]);
        }
        __syncthreads();
        bf16x8 af[4], bfr[4];
        #pragma unroll
        for (int i = 0; i < 4; ++i)
            af[i] = *(const bf16x8*)&sA[(wm + i * 16 + ml) * 32 + (q ^ swz) * 8];
        #pragma unroll
        for (int j = 0; j < 4; ++j)
            bfr[j] = *(const bf16x8*)&sB[(wn + j * 16 + ml) * 32 + (q ^ swz) * 8];
        #pragma unroll
        for (int i = 0; i < 4; ++i)
            #pragma unroll
            for (int j = 0; j < 4; ++j)
                acc[i][j] = __builtin_amdgcn_mfma_f32_16x16x32_bf16(af[i], bfr[j], acc[i][j], 0, 0, 0);
    }
    #pragma unroll
    for (int i = 0; i < 4; ++i)
        #pragma unroll
        for (int j = 0; j < 4; ++j)
            #pragma unroll
            for (int reg = 0; reg < 4; ++reg) {
                int r = row0 + wm + i * 16 + q * 4 + reg;
                int cc = col0 + wn + j * 16 + ml;
                atomicAdd(&out[(size_t)r * D_ + cc], acc[i][j][reg]);
            }
}

// Phi-chain step: out_bf16[n][f] = sum_k A[n][k]*BT[f][k], 512x512, K=1024
__global__ __launch_bounds__(256, 2) void gemm_phi(
    const bf16* __restrict__ A, int lda,
    const bf16* __restrict__ BT, int ldb,
    bf16* __restrict__ out, int ldo)
{
    __shared__ bf16 sA[128 * 32];
    __shared__ bf16 sB[128 * 32];
    const int row0 = blockIdx.x * 128, col0 = blockIdx.y * 128;
    const int tid = threadIdx.x, lane = tid & 63, wave = tid >> 6;
    const int wm = (wave & 1) * 64, wn = (wave >> 1) * 64;
    const int ml = lane & 15, q = lane >> 4;
    const int srow = lane >> 2, scol = (((lane & 3) ^ ((srow >> 1) & 3))) * 8;
    const int swz = ((ml >> 1) & 3);
    f32x4 acc[4][4] = {};

    for (int k = 0; k < 1024; k += 32) {
        __syncthreads();
        #pragma unroll
        for (int repi = 0; repi < 2; ++repi) {
            int a = wave + repi * 4;
            gll16(A  + (size_t)(row0 + a * 16 + srow) * lda + k + scol, &sA[a * 512]);
            gll16(BT + (size_t)(col0 + a * 16 + srow) * ldb + k + scol, &sB[a * 512]);
        }
        __syncthreads();
        bf16x8 af[4], bfr[4];
        #pragma unroll
        for (int i = 0; i < 4; ++i)
            af[i] = *(const bf16x8*)&sA[(wm + i * 16 + ml) * 32 + (q ^ swz) * 8];
        #pragma unroll
        for (int j = 0; j < 4; ++j)
            bfr[j] = *(const bf16x8*)&sB[(wn + j * 16 + ml) * 32 + (q ^ swz) * 8];
        #pragma unroll
        for (int i = 0; i < 4; ++i)
            #pragma unroll
            for (int j = 0; j < 4; ++j)
                acc[i][j] = __builtin_amdgcn_mfma_f32_16x16x32_bf16(af[i], bfr[j], acc[i][j], 0, 0, 0);
    }
    #pragma unroll
    for (int i = 0; i < 4; ++i)
        #pragma unroll
        for (int j = 0; j < 4; ++j)
            #pragma unroll
            for (int reg = 0; reg < 4; ++reg) {
                int r = row0 + wm + i * 16 + q * 4 + reg;
                int cc = col0 + wn + j * 16 + ml;
                out[(size_t)r * ldo + cc] = __float2bfloat16(acc[i][j][reg]);
            }
}

// Stage C: U[(b,l)][c*512+d] = sum_s wtilde_c[l-s]*u[b][s][d], triangular K-skip.
__global__ __launch_bounds__(256, 2) void gemm_toep(
    const bf16* __restrict__ W,    // pre-tiled + pre-swizzled Toeplitz blocks
    const bf16* __restrict__ uT,   // [b][512][1024]
    bf16* __restrict__ U)          // [2048][KT]
{
    __shared__ bf16 sA[128 * 32];
    __shared__ bf16 sB[128 * 32];
    const int lt = blockIdx.x;
    const int col0 = blockIdx.y * 128;
    const int c = blockIdx.z >> 1, b = blockIdx.z & 1;
    const int tid = threadIdx.x, lane = tid & 63, wave = tid >> 6;
    const int wm = (wave & 1) * 64, wn = (wave >> 1) * 64;
    const int ml = lane & 15, q = lane >> 4;
    const int srow = lane >> 2, scol = (((lane & 3) ^ ((srow >> 1) & 3))) * 8;
    const int swz = ((ml >> 1) & 3);
    f32x4 acc[4][4] = {};
    const int kend = (lt + 1) * 128;

    for (int k = 0; k < kend; k += 32) {
        int sb = k >> 7, g = lt - sb, kb = (k >> 5) & 3;
        const bf16* wt = W + (((size_t)(c * 8 + g) * 4 + kb) * 4096);
        __syncthreads();
        #pragma unroll
        for (int repi = 0; repi < 2; ++repi) {
            int a = wave + repi * 4;
            gll16(wt + a * 512 + lane * 8, &sA[a * 512]);   // pre-swizzled contiguous
            gll16(uT + ((size_t)b * D_ + col0 + a * 16 + srow) * L_ + k + scol, &sB[a * 512]);
        }
        __syncthreads();
        bf16x8 af[4], bfr[4];
        #pragma unroll
        for (int i = 0; i < 4; ++i)
            af[i] = *(const bf16x8*)&sA[(wm + i * 16 + ml) * 32 + (q ^ swz) * 8];
        #pragma unroll
        for (int j = 0; j < 4; ++j)
            bfr[j] = *(const bf16x8*)&sB[(wn + j * 16 + ml) * 32 + (q ^ swz) * 8];
        #pragma unroll
        for (int i = 0; i < 4; ++i)
            #pragma unroll
            for (int j = 0; j < 4; ++j)
                acc[i][j] = __builtin_amdgcn_mfma_f32_16x16x32_bf16(af[i], bfr[j], acc[i][j], 0, 0, 0);
    }
    #pragma unroll
    for (int i = 0; i < 4; ++i)
        #pragma unroll
        for (int j = 0; j < 4; ++j)
            #pragma unroll
            for (int reg = 0; reg < 4; ++reg) {
                int l = lt * 128 + wm + i * 16 + q * 4 + reg;
                int d = col0 + wn + j * 16 + ml;
                U[(size_t)(b * L_ + l) * KT + c * D_ + d] = __float2bfloat16(acc[i][j][reg]);
            }
}

// ---------------- launch ----------------
extern "C" void kernel_launch(void* const* d_in, const int* in_sizes, int n_in,
                              void* d_out, int out_size, void* d_ws, size_t ws_size,
                              hipStream_t stream) {
    const float* u   = (const float*)d_in[0];
    const float* fil = (const float*)d_in[1];
    const float* Mu  = (const float*)d_in[2];
    const float* My  = (const float*)d_in[3];
    const float* Mp  = (const float*)d_in[4];
    const float* Mm  = (const float*)d_in[5];
    float* out = (float*)d_out;

    char* ws = (char*)d_ws;
    size_t off = 0;
    auto alloc = [&](size_t bytes) { void* p = ws + off; off = (off + bytes + 255) & ~(size_t)255; return p; };
    bf16*  U    = (bf16*) alloc((size_t)ROWS * KT * 2);        // 73.4 MB
    bf16*  BT   = (bf16*) alloc((size_t)512 * KT * 2);         // 18.4 MB
    bf16*  PB   = (bf16*) alloc((size_t)512 * PBLD * 2);       //  3.7 MB
    bf16*  BT2  = (bf16*) alloc((size_t)512 * 1024 * 2);       //  1.0 MB
    float* z    = (float*)alloc((size_t)ROWS * D_ * 4);        //  4.2 MB
    // shared region: {W + uT} live only through gemm_toep; ZT written after
    char*  shared = (char*)alloc((size_t)1024 * 4096 * 2 + (size_t)B_ * D_ * L_ * 2); // 10.5 MB
    bf16*  W    = (bf16*)shared;                               //  8.4 MB
    bf16*  uT   = (bf16*)(shared + (size_t)1024 * 4096 * 2);   //  2.0 MB
    bf16*  ZT   = (bf16*)alloc((size_t)ROWS * ZTLD * 2) ;      // 12.6 MB (separate: shared is only 10.5)

    // preps (2 launches)
    prep_ew<<<22528, 256, 0, stream>>>(u, fil, Mu, My, U, BT, PB, W, z);
    prep_tr<<<dim3(8, 8, 35), 256, 0, stream>>>(Mp, Mm, My, u, BT, BT2, uT);

    // Phi chain: P_s = P_{s-1} N1^T + P_{s-2} N2^T, s=2..6 (tiny GEMMs)
    for (int s = 2; s <= NTAP; ++s)
        gemm_phi<<<dim3(4, 4), 256, 0, stream>>>(PB + (size_t)(s - 2) * 512, PBLD,
                                                 BT2, 1024,
                                                 PB + (size_t)s * 512, PBLD);

    // Stage C: spectral convolution (block-Toeplitz GEMM), U cols [0,16384)
    gemm_toep<<<dim3(8, 4, 64), 256, 0, stream>>>(W, uT, U);

    // Stage D: z = U_ext @ B, split-K = 16 (4 blocks/CU), atomic fp32 accumulate
    gemm_k<<<dim3(16, 4, 16), 256, 0, stream>>>(U, KT, BT, KT, z, 1120);

    // Stage R: y = z + sum_{s=1..6} shift(z,s) Phi_s  (one split-K GEMM)
    k_build_ztaps<<<(ROWS * D_ + 255) / 256, 256, 0, stream>>>(z, ZT, out);
    gemm_k<<<dim3(16, 4, 8), 256, 0, stream>>>(ZT, ZTLD, PB + 512, PBLD, out, 384);
}

// Round 4
// 343.098 us; speedup vs baseline: 1.5675x; 1.1451x over previous
//
#include <hip/hip_runtime.h>
#include <hip/hip_bf16.h>

// STU forward: spectral conv (block-Toeplitz MFMA GEMM) + big contraction GEMM
// + explicit-tap AR solve (y = sum_{s=0..6} z_{t-s} Phi_s).
// R4: double-buffered LDS K-loop (prefetch next chunk before compute),
//     split-K via plain-store partials + fused reduce (NO atomics),
//     Phi chain via pair-doubling (3 dependent launches instead of 5).
// All GEMMs bf16 MFMA 16x16x32, fp32 acc. LDS XOR swizzle -> 0 bank conflicts.
//
// Shapes: B=2, L=1024, D=512, K=16, k_u=3, k_y=2. Output (B,L,D) fp32.

using bf16 = __hip_bfloat16;
typedef __attribute__((ext_vector_type(8))) short bf16x8;
typedef __attribute__((ext_vector_type(4))) float f32x4;

#define B_   2
#define L_   1024
#define D_   512
#define K_   16
#define KT   17920      // 32*512 (phi) + 3*512 (M_u taps)
#define ROWS 2048       // B*L
#define NTAP 6          // AR taps s=1..6 (s=0 identity in fp32)
#define PBLD 3584       // PB row stride: 7 slots (s=0..6) * 512
#define ZTLD 3072       // ZT row stride: 6 taps * 512
#define SPLITD 16
#define SPLITR 8

__device__ __forceinline__ void gll16(const void* g, void* l) {
    __builtin_amdgcn_global_load_lds(
        (const __attribute__((address_space(1))) unsigned int*)g,
        (__attribute__((address_space(3))) unsigned int*)l, 16, 0, 0);
}

// ---------------- prep: merged elementwise kernel ----------------
// ranges: [0,12288) ushift | +3072 bt_mu | +2048 init_pb | +1024 wtiled | +2048 myb
__global__ void prep_ew(const float* __restrict__ u, const float* __restrict__ fil,
                        const float* __restrict__ Mu, const float* __restrict__ My,
                        bf16* __restrict__ U, bf16* __restrict__ BT,
                        bf16* __restrict__ PB, bf16* __restrict__ W,
                        bf16* __restrict__ Myb) {
    int bid = blockIdx.x, tid = threadIdx.x;
    if (bid < 12288) {                       // U_ext[r][16384+t*512+f] = u[b][l-t][f]
        int idx = bid * 256 + tid;
        int r = idx / 1536, tf = idx % 1536;
        int t = tf >> 9, f = tf & 511;
        int b = r >> 10, l = r & 1023;
        float v = (l >= t) ? u[((size_t)b * L_ + l - t) * D_ + f] : 0.f;
        U[(size_t)r * KT + 16384 + tf] = __float2bfloat16(v);
    } else if (bid < 15360) {                // BT[o][16384+tf] = M_u[o][t][f]
        int idx = (bid - 12288) * 256 + tid;
        int o = idx / 1536, tf = idx % 1536;
        BT[(size_t)o * KT + 16384 + tf] = __float2bfloat16(Mu[idx]);
    } else if (bid < 17408) {                // PB: P0 = I, P1 = M_y[:,0,:]
        int idx = (bid - 15360) * 256 + tid;
        int n = idx >> 10, c = idx & 1023;
        float v = (c < 512) ? ((n == c) ? 1.f : 0.f) : My[(size_t)n * 1024 + (c - 512)];
        PB[(size_t)n * PBLD + c] = __float2bfloat16(v);
    } else if (bid < 18432) {                // Toeplitz blocks, pre-swizzled
        int tile = bid - 17408;
        int kb = tile & 3, g = (tile >> 2) & 7, c = tile >> 5;
        int k = c & 15;
        for (int idx = tid; idx < 4096; idx += 256) {
            int i = idx >> 5, jp = idx & 31;
            int j = ((jp >> 3) ^ ((i >> 1) & 3)) * 8 + (jp & 7);
            int x = g * 128 + i - kb * 32 - j;
            float v = 0.f;
            if (x >= 0) {
                v = fil[x * K_ + k];
                if (c >= 16 && (x & 1)) v = -v;
            }
            W[(size_t)tile * 4096 + idx] = __float2bfloat16(v);
        }
    } else {                                 // Myb = bf16(My) (native layout)
        int idx = (bid - 18432) * 256 + tid;
        Myb[idx] = __float2bfloat16(My[idx]);
    }
}

// ---------------- prep: merged transpose kernel ----------------
// grid (8,8,35): z<32 bt_phi | z=32,33 BTT top half [N2|N1] | z=34 transpose_u
__global__ void prep_tr(const float* __restrict__ Mp, const float* __restrict__ Mm,
                        const float* __restrict__ My, const float* __restrict__ u,
                        bf16* __restrict__ BT, bf16* __restrict__ BTT,
                        bf16* __restrict__ uT) {
    __shared__ bf16 t[64][72];
    int zb = blockIdx.z;
    int col = threadIdx.x & 63, r0 = (threadIdx.x >> 6) * 16;
    if (zb < 32) {                           // BT[o][c*512+d] = M_c[d][o]
        int dt = blockIdx.x * 64, ot = blockIdx.y * 64, c = zb;
        const float* src = (c < 16) ? (Mp + (size_t)c * D_ * D_)
                                    : (Mm + (size_t)(c - 16) * D_ * D_);
        for (int i = 0; i < 16; ++i)
            t[r0 + i][col] = __float2bfloat16(src[(size_t)(dt + r0 + i) * D_ + ot + col]);
        __syncthreads();
        for (int i = 0; i < 16; ++i)
            BT[(size_t)(ot + r0 + i) * KT + c * D_ + dt + col] = t[col][r0 + i];
    } else if (zb < 34) {                    // BTT[f][h*512+d] = M_y[d][1-h][f]
        int h = zb - 32;
        int dt = blockIdx.x * 64, ft = blockIdx.y * 64;
        for (int i = 0; i < 16; ++i)
            t[r0 + i][col] = __float2bfloat16(My[(size_t)(dt + r0 + i) * 1024 + (1 - h) * 512 + ft + col]);
        __syncthreads();
        for (int i = 0; i < 16; ++i)
            BTT[(size_t)(ft + r0 + i) * 1024 + h * 512 + dt + col] = t[col][r0 + i];
    } else {                                 // uT[b][d][l] = u[b][l][d]
        for (int it = 0; it < 4; ++it) {
            int b = it >> 1;
            int lt = (blockIdx.x + 8 * (it & 1)) * 64, dt = blockIdx.y * 64;
            __syncthreads();
            for (int i = 0; i < 16; ++i)
                t[r0 + i][col] = __float2bfloat16(u[((size_t)b * L_ + lt + r0 + i) * D_ + dt + col]);
            __syncthreads();
            for (int i = 0; i < 16; ++i)
                uT[((size_t)b * D_ + dt + r0 + i) * L_ + lt + col] = t[col][r0 + i];
        }
    }
}

// sum 16 Stage-D partials -> z (fp32) + shifted bf16 taps ZT  (float4/thread)
__global__ void k_ztaps(const float* __restrict__ partD, float* __restrict__ z,
                        bf16* __restrict__ ZT) {
    int t = blockIdx.x * 256 + threadIdx.x;          // ROWS*D_/4 threads
    if (t >= ROWS * D_ / 4) return;
    int r = t >> 7, f4 = (t & 127) * 4;
    const float4* p = (const float4*)partD;
    float4 s = {0.f, 0.f, 0.f, 0.f};
    #pragma unroll
    for (int c = 0; c < SPLITD; ++c) {
        float4 v = p[(size_t)c * (ROWS * D_ / 4) + t];
        s.x += v.x; s.y += v.y; s.z += v.z; s.w += v.w;
    }
    ((float4*)z)[t] = s;
    ushort4 zb;
    { bf16 h;
      h = __float2bfloat16(s.x); zb.x = *(unsigned short*)&h;
      h = __float2bfloat16(s.y); zb.y = *(unsigned short*)&h;
      h = __float2bfloat16(s.z); zb.z = *(unsigned short*)&h;
      h = __float2bfloat16(s.w); zb.w = *(unsigned short*)&h; }
    int l = r & 1023;
    #pragma unroll
    for (int sh = 1; sh <= NTAP; ++sh)
        if (l + sh < 1024)
            *(ushort4*)&ZT[(size_t)(r + sh) * ZTLD + (sh - 1) * 512 + f4] = zb;
    ushort4 z4 = {0, 0, 0, 0};
    for (int sh = l + 1; sh <= NTAP; ++sh)
        *(ushort4*)&ZT[(size_t)r * ZTLD + (sh - 1) * 512 + f4] = z4;
}

// out = z + sum of 8 Stage-R partials (float4/thread)
__global__ void reduce_out(const float* __restrict__ z, const float* __restrict__ partR,
                           float* __restrict__ out) {
    int t = blockIdx.x * 256 + threadIdx.x;
    if (t >= ROWS * D_ / 4) return;
    float4 s = ((const float4*)z)[t];
    const float4* p = (const float4*)partR;
    #pragma unroll
    for (int c = 0; c < SPLITR; ++c) {
        float4 v = p[(size_t)c * (ROWS * D_ / 4) + t];
        s.x += v.x; s.y += v.y; s.z += v.z; s.w += v.w;
    }
    ((float4*)out)[t] = s;
}

// ---------------- GEMM kernels ----------------
// 128x128 tile, 256 thr = 4 waves, each wave 64x64 = 4x4 MFMA 16x16x32.
// Double-buffered LDS (2 x 8 KB per operand); XOR swizzle pg = q ^ ((row>>1)&3).

// Split-K partial GEMM: partial[z][r][n] = sum_{k in chunk z} A[r][k]*BT[n][k]
__global__ __launch_bounds__(256, 4) void gemm_k(
    const bf16* __restrict__ A, int lda,
    const bf16* __restrict__ BT, int ldb,
    float* __restrict__ part, int k_chunk)
{
    __shared__ bf16 sA[2][4096];
    __shared__ bf16 sB[2][4096];
    const int row0 = blockIdx.x * 128, col0 = blockIdx.y * 128;
    const int k0 = blockIdx.z * k_chunk, kend = k0 + k_chunk;
    const int tid = threadIdx.x, lane = tid & 63, wave = tid >> 6;
    const int wm = (wave & 1) * 64, wn = (wave >> 1) * 64;
    const int ml = lane & 15, q = lane >> 4;
    const int srow = lane >> 2, scol = (((lane & 3) ^ ((srow >> 1) & 3))) * 8;
    const int swz = ((ml >> 1) & 3);
    f32x4 acc[4][4] = {};

    const bf16* gA0 = A  + (size_t)(row0 + wave * 16      + srow) * lda + k0 + scol;
    const bf16* gA1 = A  + (size_t)(row0 + (wave + 4) * 16 + srow) * lda + k0 + scol;
    const bf16* gB0 = BT + (size_t)(col0 + wave * 16      + srow) * ldb + k0 + scol;
    const bf16* gB1 = BT + (size_t)(col0 + (wave + 4) * 16 + srow) * ldb + k0 + scol;
    gll16(gA0, &sA[0][wave * 512]); gll16(gA1, &sA[0][(wave + 4) * 512]);
    gll16(gB0, &sB[0][wave * 512]); gll16(gB1, &sB[0][(wave + 4) * 512]);

    int cur = 0;
    for (int k = k0; k < kend; k += 32) {
        gA0 += 32; gA1 += 32; gB0 += 32; gB1 += 32;
        __syncthreads();                      // drains staging of buf 'cur'
        if (k + 32 < kend) {                  // prefetch next chunk into other buf
            int nb = cur ^ 1;
            gll16(gA0, &sA[nb][wave * 512]); gll16(gA1, &sA[nb][(wave + 4) * 512]);
            gll16(gB0, &sB[nb][wave * 512]); gll16(gB1, &sB[nb][(wave + 4) * 512]);
        }
        bf16x8 af[4], bfr[4];
        #pragma unroll
        for (int i = 0; i < 4; ++i)
            af[i] = *(const bf16x8*)&sA[cur][(wm + i * 16 + ml) * 32 + (q ^ swz) * 8];
        #pragma unroll
        for (int j = 0; j < 4; ++j)
            bfr[j] = *(const bf16x8*)&sB[cur][(wn + j * 16 + ml) * 32 + (q ^ swz) * 8];
        #pragma unroll
        for (int i = 0; i < 4; ++i)
            #pragma unroll
            for (int j = 0; j < 4; ++j)
                acc[i][j] = __builtin_amdgcn_mfma_f32_16x16x32_bf16(af[i], bfr[j], acc[i][j], 0, 0, 0);
        cur ^= 1;
    }
    float* o = part + (size_t)blockIdx.z * ROWS * D_;
    #pragma unroll
    for (int i = 0; i < 4; ++i)
        #pragma unroll
        for (int j = 0; j < 4; ++j)
            #pragma unroll
            for (int reg = 0; reg < 4; ++reg) {
                int r = row0 + wm + i * 16 + q * 4 + reg;
                int cc = col0 + wn + j * 16 + ml;
                o[(size_t)r * D_ + cc] = acc[i][j][reg];
            }
}

// ---- shared body for small bf16-out GEMMs (Phi chain) ----
__device__ __forceinline__ void phi_body(
    const bf16* A, int lda, const bf16* BT, int ldb,
    bf16* out, int ldo, int klen, const bf16* add, int lad,
    int row0, int col0)
{
    __shared__ bf16 sA[4096];
    __shared__ bf16 sB[4096];
    const int tid = threadIdx.x, lane = tid & 63, wave = tid >> 6;
    const int wm = (wave & 1) * 64, wn = (wave >> 1) * 64;
    const int ml = lane & 15, q = lane >> 4;
    const int srow = lane >> 2, scol = (((lane & 3) ^ ((srow >> 1) & 3))) * 8;
    const int swz = ((ml >> 1) & 3);
    f32x4 acc[4][4] = {};

    for (int k = 0; k < klen; k += 32) {
        __syncthreads();
        #pragma unroll
        for (int repi = 0; repi < 2; ++repi) {
            int a = wave + repi * 4;
            gll16(A  + (size_t)(row0 + a * 16 + srow) * lda + k + scol, &sA[a * 512]);
            gll16(BT + (size_t)(col0 + a * 16 + srow) * ldb + k + scol, &sB[a * 512]);
        }
        __syncthreads();
        bf16x8 af[4], bfr[4];
        #pragma unroll
        for (int i = 0; i < 4; ++i)
            af[i] = *(const bf16x8*)&sA[(wm + i * 16 + ml) * 32 + (q ^ swz) * 8];
        #pragma unroll
        for (int j = 0; j < 4; ++j)
            bfr[j] = *(const bf16x8*)&sB[(wn + j * 16 + ml) * 32 + (q ^ swz) * 8];
        #pragma unroll
        for (int i = 0; i < 4; ++i)
            #pragma unroll
            for (int j = 0; j < 4; ++j)
                acc[i][j] = __builtin_amdgcn_mfma_f32_16x16x32_bf16(af[i], bfr[j], acc[i][j], 0, 0, 0);
    }
    #pragma unroll
    for (int i = 0; i < 4; ++i)
        #pragma unroll
        for (int j = 0; j < 4; ++j)
            #pragma unroll
            for (int reg = 0; reg < 4; ++reg) {
                int r = row0 + wm + i * 16 + q * 4 + reg;
                int cc = col0 + wn + j * 16 + ml;
                float v = acc[i][j][reg];
                if (add) v += __bfloat162float(add[(size_t)r * lad + cc]);
                out[(size_t)r * ldo + cc] = __float2bfloat16(v);
            }
}

__global__ __launch_bounds__(256, 2) void gemm_phi(
    const bf16* A, int lda, const bf16* BT, int ldb,
    bf16* out, int ldo, int klen)
{
    phi_body(A, lda, BT, ldb, out, ldo, klen, nullptr, 0,
             blockIdx.x * 128, blockIdx.y * 128);
}

// merged independent sub-GEMMs: z=0 P2 | z=1 X1=N1*N2 | z=2 X2=N1^2+N2
__global__ __launch_bounds__(256, 2) void phi_misc(
    const bf16* PB, const bf16* BTT, const bf16* Myb, bf16* BTTw, bf16* PBw)
{
    int row0 = (blockIdx.x & 3) * 128, col0 = blockIdx.y * 128;
    int which = blockIdx.x >> 2;
    if (which == 0)         // P2 = [P0|P1] x BTT(top): out PB slot 2
        phi_body(PB, PBLD, BTT, 1024, PBw + 2 * 512, PBLD, 1024, nullptr, 0, row0, col0);
    else if (which == 1)    // X1 = N1*N2 -> BTT bottom-left
        phi_body(BTT + 512, 1024, Myb + 512, 1024,
                 BTTw + (size_t)512 * 1024, 1024, 512, nullptr, 0, row0, col0);
    else                    // X2 = N1*N1 + N2 -> BTT bottom-right
        phi_body(BTT + 512, 1024, Myb, 1024,
                 BTTw + (size_t)512 * 1024 + 512, 1024, 512, BTT, 1024, row0, col0);
}

// Stage C: U[(b,l)][c*512+d] = sum_s wtilde_c[l-s]*u[b][s][d], triangular K-skip,
// double-buffered.
__global__ __launch_bounds__(256, 4) void gemm_toep(
    const bf16* __restrict__ W,    // pre-tiled + pre-swizzled Toeplitz blocks
    const bf16* __restrict__ uT,   // [b][512][1024]
    bf16* __restrict__ U)          // [2048][KT]
{
    __shared__ bf16 sA[2][4096];
    __shared__ bf16 sB[2][4096];
    const int lt = blockIdx.x;
    const int col0 = blockIdx.y * 128;
    const int c = blockIdx.z >> 1, b = blockIdx.z & 1;
    const int tid = threadIdx.x, lane = tid & 63, wave = tid >> 6;
    const int wm = (wave & 1) * 64, wn = (wave >> 1) * 64;
    const int ml = lane & 15, q = lane >> 4;
    const int srow = lane >> 2, scol = (((lane & 3) ^ ((srow >> 1) & 3))) * 8;
    const int swz = ((ml >> 1) & 3);
    f32x4 acc[4][4] = {};
    const int kend = (lt + 1) * 128;

    const bf16* gB0 = uT + ((size_t)b * D_ + col0 + wave * 16      + srow) * L_ + scol;
    const bf16* gB1 = uT + ((size_t)b * D_ + col0 + (wave + 4) * 16 + srow) * L_ + scol;
    auto wptr = [&](int kk) {
        int g = lt - (kk >> 7), kb = (kk >> 5) & 3;
        return W + (((size_t)(c * 8 + g) * 4 + kb) * 4096);
    };
    { const bf16* wt = wptr(0);
      gll16(wt + wave * 512 + lane * 8, &sA[0][wave * 512]);
      gll16(wt + (wave + 4) * 512 + lane * 8, &sA[0][(wave + 4) * 512]);
      gll16(gB0, &sB[0][wave * 512]); gll16(gB1, &sB[0][(wave + 4) * 512]); }

    int cur = 0;
    for (int k = 0; k < kend; k += 32) {
        gB0 += 32; gB1 += 32;
        __syncthreads();
        if (k + 32 < kend) {
            int nb = cur ^ 1;
            const bf16* wt = wptr(k + 32);
            gll16(wt + wave * 512 + lane * 8, &sA[nb][wave * 512]);
            gll16(wt + (wave + 4) * 512 + lane * 8, &sA[nb][(wave + 4) * 512]);
            gll16(gB0, &sB[nb][wave * 512]); gll16(gB1, &sB[nb][(wave + 4) * 512]);
        }
        bf16x8 af[4], bfr[4];
        #pragma unroll
        for (int i = 0; i < 4; ++i)
            af[i] = *(const bf16x8*)&sA[cur][(wm + i * 16 + ml) * 32 + (q ^ swz) * 8];
        #pragma unroll
        for (int j = 0; j < 4; ++j)
            bfr[j] = *(const bf16x8*)&sB[cur][(wn + j * 16 + ml) * 32 + (q ^ swz) * 8];
        #pragma unroll
        for (int i = 0; i < 4; ++i)
            #pragma unroll
            for (int j = 0; j < 4; ++j)
                acc[i][j] = __builtin_amdgcn_mfma_f32_16x16x32_bf16(af[i], bfr[j], acc[i][j], 0, 0, 0);
        cur ^= 1;
    }
    #pragma unroll
    for (int i = 0; i < 4; ++i)
        #pragma unroll
        for (int j = 0; j < 4; ++j)
            #pragma unroll
            for (int reg = 0; reg < 4; ++reg) {
                int l = lt * 128 + wm + i * 16 + q * 4 + reg;
                int d = col0 + wn + j * 16 + ml;
                U[(size_t)(b * L_ + l) * KT + c * D_ + d] = __float2bfloat16(acc[i][j][reg]);
            }
}

// ---------------- launch ----------------
extern "C" void kernel_launch(void* const* d_in, const int* in_sizes, int n_in,
                              void* d_out, int out_size, void* d_ws, size_t ws_size,
                              hipStream_t stream) {
    const float* u   = (const float*)d_in[0];
    const float* fil = (const float*)d_in[1];
    const float* Mu  = (const float*)d_in[2];
    const float* My  = (const float*)d_in[3];
    const float* Mp  = (const float*)d_in[4];
    const float* Mm  = (const float*)d_in[5];
    float* out = (float*)d_out;

    char* ws = (char*)d_ws;
    size_t off = 0;
    auto alloc = [&](size_t bytes) { void* p = ws + off; off = (off + bytes + 255) & ~(size_t)255; return p; };
    bf16*  U    = (bf16*) alloc((size_t)ROWS * KT * 2);        // 73.4 MB
    bf16*  BT   = (bf16*) alloc((size_t)512 * KT * 2);         // 18.4 MB
    bf16*  PB   = (bf16*) alloc((size_t)512 * PBLD * 2);       //  3.7 MB
    bf16*  BTT  = (bf16*) alloc((size_t)1024 * 1024 * 2);      //  2.1 MB
    bf16*  Myb  = (bf16*) alloc((size_t)512 * 1024 * 2);       //  1.0 MB
    float* z    = (float*)alloc((size_t)ROWS * D_ * 4);        //  4.2 MB
    bf16*  ZT   = (bf16*) alloc((size_t)ROWS * ZTLD * 2);      // 12.6 MB
    // overlapped region: {W + uT} dead after gemm_toep; partD written after;
    // partD dead after k_ztaps; partR written after.
    char*  region = (char*)alloc((size_t)SPLITD * ROWS * D_ * 4); // 64 MB
    bf16*  W    = (bf16*)region;                               //  8.4 MB
    bf16*  uT   = (bf16*)(region + (size_t)1024 * 4096 * 2);   //  2.0 MB
    float* partD = (float*)region;                             // 64 MB
    float* partR = (float*)region;                             // 32 MB

    // preps (2 launches)
    prep_ew<<<20480, 256, 0, stream>>>(u, fil, Mu, My, U, BT, PB, W, Myb);
    prep_tr<<<dim3(8, 8, 35), 256, 0, stream>>>(Mp, Mm, My, u, BT, BTT, uT);

    // Phi chain via pair-doubling: 3 dependent launches
    phi_misc<<<dim3(12, 4), 256, 0, stream>>>(PB, BTT, Myb, BTT, PB);
    gemm_phi<<<dim3(4, 8), 256, 0, stream>>>(PB + 512,     PBLD, BTT, 1024,
                                             PB + 3 * 512, PBLD, 1024);  // [P3|P4]
    gemm_phi<<<dim3(4, 8), 256, 0, stream>>>(PB + 3 * 512, PBLD, BTT, 1024,
                                             PB + 5 * 512, PBLD, 1024);  // [P5|P6]

    // Stage C: spectral conv (block-Toeplitz GEMM), U cols [0,16384)
    gemm_toep<<<dim3(8, 4, 64), 256, 0, stream>>>(W, uT, U);

    // Stage D: z-partials = U_ext @ B, split-K 16, plain stores
    gemm_k<<<dim3(16, 4, SPLITD), 256, 0, stream>>>(U, KT, BT, KT, partD, KT / SPLITD);

    // reduce partials -> z, build shifted taps
    k_ztaps<<<(ROWS * D_ / 4 + 255) / 256, 256, 0, stream>>>(partD, z, ZT);

    // Stage R: tap-partials = ZT @ PhiT, split-K 8
    gemm_k<<<dim3(16, 4, SPLITR), 256, 0, stream>>>(ZT, ZTLD, PB + 512, PBLD,
                                                    partR, ZTLD / SPLITR);

    // out = z + sum partR
    reduce_out<<<(ROWS * D_ / 4 + 255) / 256, 256, 0, stream>>>(z, partR, out);
}

// Round 6
// 286.261 us; speedup vs baseline: 1.8787x; 1.1985x over previous
//
#include <hip/hip_runtime.h>
#include <hip/hip_bf16.h>

// STU forward. R6 = R5 structure with NTAP restored to 6:
//  - Parity-split spectral conv: z = A_e(Mp+Mm) + A_o(Mp-Mm); A_e/A_o are
//    even/odd-tap partial convs, decimated 2x in both l and s -> Stage C
//    MFMA work halves (4 Toeplitz convs over 512-frames, triangular K).
//  - NTAP=6 explicit-tap AR. Phi chain: phi_misc (fused into conv launch),
//    doubling1 [P3|P4] (fused into Stage D), doubling2 [P5|P6] (fused into
//    k_ztaps). 7 launches total.
//  - All GEMMs bf16 MFMA 16x16x32 fp32 acc, dbuf LDS, XOR swizzle (0 conflicts).

using bf16 = __hip_bfloat16;
typedef __attribute__((ext_vector_type(8))) short bf16x8;
typedef __attribute__((ext_vector_type(4))) float f32x4;

#define B_   2
#define L_   1024
#define D_   512
#define K_   16
#define KT   17920      // 32*512 (conv channels) + 3*512 (M_u taps)
#define ROWS 2048       // B*L
#define NTAP 6          // AR taps s=1..6 (s=0 identity in fp32)
#define PBLD 3584       // PB row stride: 7 slots (s=0..6) * 512
#define ZTLD 3072       // ZT row stride: 6 taps * 512
#define SPLITD 16
#define SPLITR 8

__device__ __forceinline__ void gll16(const void* g, void* l) {
    __builtin_amdgcn_global_load_lds(
        (const __attribute__((address_space(1))) unsigned int*)g,
        (__attribute__((address_space(3))) unsigned int*)l, 16, 0, 0);
}

// ---------------- prep: merged elementwise (vectorized) ----------------
// blocks: [0,3072) ushift | [3072,3840) bt_mu | [3840,4352) init_pb
//         [4352,5120) W build | [5120,5632) Myb
__global__ void prep_ew(const float* __restrict__ u, const float* __restrict__ fil,
                        const float* __restrict__ Mu, const float* __restrict__ My,
                        bf16* __restrict__ U, bf16* __restrict__ BT,
                        bf16* __restrict__ PB, bf16* __restrict__ W,
                        bf16* __restrict__ Myb) {
    int bid = blockIdx.x, tid = threadIdx.x;
    auto pack4 = [](float4 v) {
        ushort4 o; bf16 h;
        h = __float2bfloat16(v.x); o.x = *(unsigned short*)&h;
        h = __float2bfloat16(v.y); o.y = *(unsigned short*)&h;
        h = __float2bfloat16(v.z); o.z = *(unsigned short*)&h;
        h = __float2bfloat16(v.w); o.w = *(unsigned short*)&h;
        return o;
    };
    if (bid < 3072) {                        // U taps: U[r][16384+t*512+f]=u[b][l-t][f]
        int e4 = bid * 256 + tid;
        int r = e4 / 384, rem = e4 % 384;
        int t = rem >> 7, f = (rem & 127) * 4;
        int b = r >> 10, l = r & 1023;
        float4 v = {0.f, 0.f, 0.f, 0.f};
        if (l >= t) v = *(const float4*)&u[((size_t)b * L_ + l - t) * D_ + f];
        *(ushort4*)&U[(size_t)r * KT + 16384 + t * 512 + f] = pack4(v);
    } else if (bid < 3840) {                 // BT taps: BT[o][16384+tf]=M_u[o][t][f]
        int e4 = (bid - 3072) * 256 + tid;
        int o = e4 / 384, tf4 = (e4 % 384) * 4;
        float4 v = *(const float4*)&Mu[(size_t)o * 1536 + tf4];
        *(ushort4*)&BT[(size_t)o * KT + 16384 + tf4] = pack4(v);
    } else if (bid < 4352) {                 // PB: P0=I, P1=M_y[:,0,:]
        int e4 = (bid - 3840) * 256 + tid;
        int n = e4 >> 8, c4 = (e4 & 255) * 4;
        float4 v;
        if (c4 < 512) {
            v.x = (n == c4) ? 1.f : 0.f;     v.y = (n == c4 + 1) ? 1.f : 0.f;
            v.z = (n == c4 + 2) ? 1.f : 0.f; v.w = (n == c4 + 3) ? 1.f : 0.f;
        } else v = *(const float4*)&My[(size_t)n * 1024 + (c4 - 512)];
        *(ushort4*)&PB[(size_t)n * PBLD + c4] = pack4(v);
    } else if (bid < 5120) {                 // Toeplitz W tiles (3 sets), pre-swizzled
        int tile = bid - 4352;               // [set3][k16][g4][kb4]
        int set = tile >> 8, rem = tile & 255;
        int k = rem >> 4, g = (rem >> 2) & 3, kb = rem & 3;
        for (int idx = tid; idx < 4096; idx += 256) {
            int i = idx >> 5, jp = idx & 31;
            int j = ((jp >> 3) ^ ((i >> 1) & 3)) * 8 + (jp & 7);
            int x = g * 128 + i - kb * 32 - j - (set == 2 ? 1 : 0);
            float v = 0.f;
            if (x >= 0) {
                int row = (set == 0) ? 2 * x : 2 * x + 1;   // ve / vo
                v = fil[row * K_ + k];
            }
            W[(size_t)tile * 4096 + idx] = __float2bfloat16(v);
        }
    } else {                                 // Myb = bf16(My), native layout
        int e4 = (bid - 5120) * 256 + tid;
        float4 v = *(const float4*)&My[(size_t)e4 * 4];
        *(ushort4*)&Myb[(size_t)e4 * 4] = pack4(v);
    }
}

// ---------------- prep: merged transposes ----------------
// grid (8,8,35): z<32 BT conv-channels (Msum/Mdiff) | z=32,33 BTT top | z=34 uPT
__global__ void prep_tr(const float* __restrict__ Mp, const float* __restrict__ Mm,
                        const float* __restrict__ My, const float* __restrict__ u,
                        bf16* __restrict__ BT, bf16* __restrict__ BTT,
                        bf16* __restrict__ uPT) {
    __shared__ bf16 t[64][72];
    int zb = blockIdx.z;
    int col = threadIdx.x & 63, r0 = (threadIdx.x >> 6) * 16;
    if (zb < 32) {                           // BT[o][c*512+d] = (Mp +/- Mm)[k][d][o]
        int dt = blockIdx.x * 64, ot = blockIdx.y * 64, c = zb;
        int k = c & 15;
        const float* sp = Mp + (size_t)k * D_ * D_;
        const float* sm = Mm + (size_t)k * D_ * D_;
        float sg = (c < 16) ? 1.f : -1.f;
        for (int i = 0; i < 16; ++i) {
            size_t o_ = (size_t)(dt + r0 + i) * D_ + ot + col;
            t[r0 + i][col] = __float2bfloat16(sp[o_] + sg * sm[o_]);
        }
        __syncthreads();
        for (int i = 0; i < 16; ++i)
            BT[(size_t)(ot + r0 + i) * KT + c * D_ + dt + col] = t[col][r0 + i];
    } else if (zb < 34) {                    // BTT[f][h*512+d] = M_y[d][1-h][f]
        int h = zb - 32;
        int dt = blockIdx.x * 64, ft = blockIdx.y * 64;
        for (int i = 0; i < 16; ++i)
            t[r0 + i][col] = __float2bfloat16(My[(size_t)(dt + r0 + i) * 1024 + (1 - h) * 512 + ft + col]);
        __syncthreads();
        for (int i = 0; i < 16; ++i)
            BTT[(size_t)(ft + r0 + i) * 1024 + h * 512 + dt + col] = t[col][r0 + i];
    } else {                                 // uPT[b][p][d][m'] = u[b][2m'+p][d]
        for (int it = 0; it < 4; ++it) {     // it = b*2+p
            int b = it >> 1, p = it & 1;
            int mt = blockIdx.x * 64, dt = blockIdx.y * 64;
            __syncthreads();
            for (int i = 0; i < 16; ++i)
                t[r0 + i][col] = __float2bfloat16(u[((size_t)b * L_ + 2 * (mt + r0 + i) + p) * D_ + dt + col]);
            __syncthreads();
            for (int i = 0; i < 16; ++i)
                uPT[((size_t)it * 512 + dt + r0 + i) * 512 + mt + col] = t[col][r0 + i];
        }
    }
}

// ---- shared body for small bf16-out GEMMs (uses caller LDS) ----
__device__ __forceinline__ void phi_body(
    const bf16* A, int lda, const bf16* BT, int ldb,
    bf16* out, int ldo, int klen, const bf16* add, int lad,
    int row0, int col0, bf16* sA, bf16* sB)
{
    const int tid = threadIdx.x, lane = tid & 63, wave = tid >> 6;
    const int wm = (wave & 1) * 64, wn = (wave >> 1) * 64;
    const int ml = lane & 15, q = lane >> 4;
    const int srow = lane >> 2, scol = (((lane & 3) ^ ((srow >> 1) & 3))) * 8;
    const int swz = ((ml >> 1) & 3);
    f32x4 acc[4][4] = {};

    for (int k = 0; k < klen; k += 32) {
        __syncthreads();
        #pragma unroll
        for (int repi = 0; repi < 2; ++repi) {
            int a = wave + repi * 4;
            gll16(A  + (size_t)(row0 + a * 16 + srow) * lda + k + scol, &sA[a * 512]);
            gll16(BT + (size_t)(col0 + a * 16 + srow) * ldb + k + scol, &sB[a * 512]);
        }
        __syncthreads();
        bf16x8 af[4], bfr[4];
        #pragma unroll
        for (int i = 0; i < 4; ++i)
            af[i] = *(const bf16x8*)&sA[(wm + i * 16 + ml) * 32 + (q ^ swz) * 8];
        #pragma unroll
        for (int j = 0; j < 4; ++j)
            bfr[j] = *(const bf16x8*)&sB[(wn + j * 16 + ml) * 32 + (q ^ swz) * 8];
        #pragma unroll
        for (int i = 0; i < 4; ++i)
            #pragma unroll
            for (int j = 0; j < 4; ++j)
                acc[i][j] = __builtin_amdgcn_mfma_f32_16x16x32_bf16(af[i], bfr[j], acc[i][j], 0, 0, 0);
    }
    #pragma unroll
    for (int i = 0; i < 4; ++i)
        #pragma unroll
        for (int j = 0; j < 4; ++j)
            #pragma unroll
            for (int reg = 0; reg < 4; ++reg) {
                int r = row0 + wm + i * 16 + q * 4 + reg;
                int cc = col0 + wn + j * 16 + ml;
                float v = acc[i][j][reg];
                if (add) v += __bfloat162float(add[(size_t)r * lad + cc]);
                out[(size_t)r * ldo + cc] = __float2bfloat16(v);
            }
}

// sum 16 Stage-D partials -> z (fp32) + shifted bf16 taps ZT
// + fused Phi doubling2: blocks [1024,1056) compute [P5|P6] = [P3|P4] x BTT
__global__ void k_ztaps(const float* __restrict__ partD, float* __restrict__ z,
                        bf16* __restrict__ ZT, bf16* PB, const bf16* BTT) {
    __shared__ bf16 sA[4096];
    __shared__ bf16 sB[4096];
    int bid = blockIdx.x;
    if (bid >= 1024) {
        int x = bid - 1024;                  // 32 blocks: 4 row tiles x 8 col tiles
        int row0 = (x & 3) * 128, col0 = (x >> 2) * 128;
        phi_body(PB + 3 * 512, PBLD, BTT, 1024, PB + 5 * 512, PBLD, 1024,
                 nullptr, 0, row0, col0, sA, sB);
        return;
    }
    int t = bid * 256 + threadIdx.x;         // ROWS*D_/4 threads exactly
    int r = t >> 7, f4 = (t & 127) * 4;
    const float4* p = (const float4*)partD;
    float4 s = {0.f, 0.f, 0.f, 0.f};
    #pragma unroll
    for (int c = 0; c < SPLITD; ++c) {
        float4 v = p[(size_t)c * (ROWS * D_ / 4) + t];
        s.x += v.x; s.y += v.y; s.z += v.z; s.w += v.w;
    }
    ((float4*)z)[t] = s;
    ushort4 zb;
    { bf16 h;
      h = __float2bfloat16(s.x); zb.x = *(unsigned short*)&h;
      h = __float2bfloat16(s.y); zb.y = *(unsigned short*)&h;
      h = __float2bfloat16(s.z); zb.z = *(unsigned short*)&h;
      h = __float2bfloat16(s.w); zb.w = *(unsigned short*)&h; }
    int l = r & 1023;
    #pragma unroll
    for (int sh = 1; sh <= NTAP; ++sh)
        if (l + sh < 1024)
            *(ushort4*)&ZT[(size_t)(r + sh) * ZTLD + (sh - 1) * 512 + f4] = zb;
    ushort4 z4 = {0, 0, 0, 0};
    for (int sh = l + 1; sh <= NTAP; ++sh)
        *(ushort4*)&ZT[(size_t)r * ZTLD + (sh - 1) * 512 + f4] = z4;
}

// out = z + sum of SPLITR Stage-R partials
__global__ void reduce_out(const float* __restrict__ z, const float* __restrict__ partR,
                           float* __restrict__ out) {
    int t = blockIdx.x * 256 + threadIdx.x;
    if (t >= ROWS * D_ / 4) return;
    float4 s = ((const float4*)z)[t];
    const float4* p = (const float4*)partR;
    #pragma unroll
    for (int c = 0; c < SPLITR; ++c) {
        float4 v = p[(size_t)c * (ROWS * D_ / 4) + t];
        s.x += v.x; s.y += v.y; s.z += v.z; s.w += v.w;
    }
    ((float4*)out)[t] = s;
}

// ---------------- Stage C: parity-split conv (+ fused phi_misc) ----------------
// grid (4 mt, 4 dt, 131). z<128: conv type t=z&3, b=(z>>2)&1, k=z>>3.
//  t0: A_e@even l, u0, We | t1: A_e@odd l, u1, We
//  t2: A_o@odd l,  u0, Wo | t3: A_o@even l, u1, Wo_shift(-1)
// z=128..130: phi_misc {P2, X1, X2}.
__global__ __launch_bounds__(256, 4) void conv_misc(
    const bf16* __restrict__ W, const bf16* __restrict__ uPT,
    bf16* __restrict__ U,
    const bf16* PB, const bf16* BTT, const bf16* Myb)
{
    __shared__ bf16 sA[2][4096];
    __shared__ bf16 sB[2][4096];
    const int z = blockIdx.z;
    if (z >= 128) {
        int which = z - 128;
        int row0 = blockIdx.x * 128, col0 = blockIdx.y * 128;
        bf16* BTTw = (bf16*)BTT; bf16* PBw = (bf16*)PB;
        if (which == 0)        // P2 = [P0|P1] x BTT(top)
            phi_body(PB, PBLD, BTT, 1024, PBw + 2 * 512, PBLD, 1024,
                     nullptr, 0, row0, col0, &sA[0][0], &sB[0][0]);
        else if (which == 1)   // X1 -> BTT rows 512+, cols 0..511
            phi_body(BTT + 512, 1024, Myb + 512, 1024,
                     BTTw + (size_t)512 * 1024, 1024, 512,
                     nullptr, 0, row0, col0, &sA[0][0], &sB[0][0]);
        else                   // X2 -> BTT rows 512+, cols 512+
            phi_body(BTT + 512, 1024, Myb, 1024,
                     BTTw + (size_t)512 * 1024 + 512, 1024, 512,
                     BTT, 1024, row0, col0, &sA[0][0], &sB[0][0]);
        return;
    }
    const int mt = blockIdx.x, dt = blockIdx.y * 128;
    const int t = z & 3, b = (z >> 2) & 1, k = z >> 3;
    const int pb_ = t & 1;                       // input u parity
    const int p = (t & 1) ^ (t >> 1);            // output parity: 0,1,1,0
    const int set = (t < 2) ? 0 : (t == 2 ? 1 : 2);
    const int ch = (t < 2) ? k : 16 + k;
    const int plane = b * 2 + pb_;
    const int tid = threadIdx.x, lane = tid & 63, wave = tid >> 6;
    const int wm = (wave & 1) * 64, wn = (wave >> 1) * 64;
    const int ml = lane & 15, q = lane >> 4;
    const int srow = lane >> 2, scol = (((lane & 3) ^ ((srow >> 1) & 3))) * 8;
    const int swz = ((ml >> 1) & 3);
    f32x4 acc[4][4] = {};
    const int kend = (mt + 1) * 128;

    const bf16* gB0 = uPT + ((size_t)plane * 512 + dt + wave * 16       + srow) * 512 + scol;
    const bf16* gB1 = uPT + ((size_t)plane * 512 + dt + (wave + 4) * 16 + srow) * 512 + scol;
    auto wptr = [&](int kk) {
        int g = mt - (kk >> 7), kb = (kk >> 5) & 3;
        return W + (((size_t)(set * 16 + k) * 16 + g * 4 + kb) * 4096);
    };
    { const bf16* wt = wptr(0);
      gll16(wt + wave * 512 + lane * 8, &sA[0][wave * 512]);
      gll16(wt + (wave + 4) * 512 + lane * 8, &sA[0][(wave + 4) * 512]);
      gll16(gB0, &sB[0][wave * 512]); gll16(gB1, &sB[0][(wave + 4) * 512]); }

    int cur = 0;
    for (int kk = 0; kk < kend; kk += 32) {
        gB0 += 32; gB1 += 32;
        __syncthreads();
        if (kk + 32 < kend) {
            int nb = cur ^ 1;
            const bf16* wt = wptr(kk + 32);
            gll16(wt + wave * 512 + lane * 8, &sA[nb][wave * 512]);
            gll16(wt + (wave + 4) * 512 + lane * 8, &sA[nb][(wave + 4) * 512]);
            gll16(gB0, &sB[nb][wave * 512]); gll16(gB1, &sB[nb][(wave + 4) * 512]);
        }
        bf16x8 af[4], bfr[4];
        #pragma unroll
        for (int i = 0; i < 4; ++i)
            af[i] = *(const bf16x8*)&sA[cur][(wm + i * 16 + ml) * 32 + (q ^ swz) * 8];
        #pragma unroll
        for (int j = 0; j < 4; ++j)
            bfr[j] = *(const bf16x8*)&sB[cur][(wn + j * 16 + ml) * 32 + (q ^ swz) * 8];
        #pragma unroll
        for (int i = 0; i < 4; ++i)
            #pragma unroll
            for (int j = 0; j < 4; ++j)
                acc[i][j] = __builtin_amdgcn_mfma_f32_16x16x32_bf16(af[i], bfr[j], acc[i][j], 0, 0, 0);
        cur ^= 1;
    }
    #pragma unroll
    for (int i = 0; i < 4; ++i)
        #pragma unroll
        for (int j = 0; j < 4; ++j)
            #pragma unroll
            for (int reg = 0; reg < 4; ++reg) {
                int m = mt * 128 + wm + i * 16 + q * 4 + reg;
                int l = 2 * m + p;
                int d = dt + wn + j * 16 + ml;
                U[(size_t)(b * L_ + l) * KT + ch * 512 + d] = __float2bfloat16(acc[i][j][reg]);
            }
}

// ---------------- split-K partial GEMM (+ optional fused doubling slice) ----
__global__ __launch_bounds__(256, 4) void gemm_k(
    const bf16* __restrict__ A, int lda,
    const bf16* __restrict__ BT, int ldb,
    float* __restrict__ part, int k_chunk, int nsplit,
    const bf16* PB, const bf16* BTT)
{
    __shared__ bf16 sA[2][4096];
    __shared__ bf16 sB[2][4096];
    if ((int)blockIdx.z == nsplit) {          // doubling1: [P3|P4] = [P1|P2] x BTT
        int x = blockIdx.x;
        if (x >= 8) return;
        int row0 = (x & 3) * 128;
        int col0 = (((x >> 2) * 4) + blockIdx.y) * 128;
        phi_body(PB + 512, PBLD, BTT, 1024, (bf16*)PB + 3 * 512, PBLD, 1024,
                 nullptr, 0, row0, col0, &sA[0][0], &sB[0][0]);
        return;
    }
    const int row0 = blockIdx.x * 128, col0 = blockIdx.y * 128;
    const int k0 = blockIdx.z * k_chunk, kend = k0 + k_chunk;
    const int tid = threadIdx.x, lane = tid & 63, wave = tid >> 6;
    const int wm = (wave & 1) * 64, wn = (wave >> 1) * 64;
    const int ml = lane & 15, q = lane >> 4;
    const int srow = lane >> 2, scol = (((lane & 3) ^ ((srow >> 1) & 3))) * 8;
    const int swz = ((ml >> 1) & 3);
    f32x4 acc[4][4] = {};

    const bf16* gA0 = A  + (size_t)(row0 + wave * 16       + srow) * lda + k0 + scol;
    const bf16* gA1 = A  + (size_t)(row0 + (wave + 4) * 16 + srow) * lda + k0 + scol;
    const bf16* gB0 = BT + (size_t)(col0 + wave * 16       + srow) * ldb + k0 + scol;
    const bf16* gB1 = BT + (size_t)(col0 + (wave + 4) * 16 + srow) * ldb + k0 + scol;
    gll16(gA0, &sA[0][wave * 512]); gll16(gA1, &sA[0][(wave + 4) * 512]);
    gll16(gB0, &sB[0][wave * 512]); gll16(gB1, &sB[0][(wave + 4) * 512]);

    int cur = 0;
    for (int k = k0; k < kend; k += 32) {
        gA0 += 32; gA1 += 32; gB0 += 32; gB1 += 32;
        __syncthreads();
        if (k + 32 < kend) {
            int nb = cur ^ 1;
            gll16(gA0, &sA[nb][wave * 512]); gll16(gA1, &sA[nb][(wave + 4) * 512]);
            gll16(gB0, &sB[nb][wave * 512]); gll16(gB1, &sB[nb][(wave + 4) * 512]);
        }
        bf16x8 af[4], bfr[4];
        #pragma unroll
        for (int i = 0; i < 4; ++i)
            af[i] = *(const bf16x8*)&sA[cur][(wm + i * 16 + ml) * 32 + (q ^ swz) * 8];
        #pragma unroll
        for (int j = 0; j < 4; ++j)
            bfr[j] = *(const bf16x8*)&sB[cur][(wn + j * 16 + ml) * 32 + (q ^ swz) * 8];
        #pragma unroll
        for (int i = 0; i < 4; ++i)
            #pragma unroll
            for (int j = 0; j < 4; ++j)
                acc[i][j] = __builtin_amdgcn_mfma_f32_16x16x32_bf16(af[i], bfr[j], acc[i][j], 0, 0, 0);
        cur ^= 1;
    }
    float* o = part + (size_t)blockIdx.z * ROWS * D_;
    #pragma unroll
    for (int i = 0; i < 4; ++i)
        #pragma unroll
        for (int j = 0; j < 4; ++j)
            #pragma unroll
            for (int reg = 0; reg < 4; ++reg) {
                int r = row0 + wm + i * 16 + q * 4 + reg;
                int cc = col0 + wn + j * 16 + ml;
                o[(size_t)r * D_ + cc] = acc[i][j][reg];
            }
}

// ---------------- launch ----------------
extern "C" void kernel_launch(void* const* d_in, const int* in_sizes, int n_in,
                              void* d_out, int out_size, void* d_ws, size_t ws_size,
                              hipStream_t stream) {
    const float* u   = (const float*)d_in[0];
    const float* fil = (const float*)d_in[1];
    const float* Mu  = (const float*)d_in[2];
    const float* My  = (const float*)d_in[3];
    const float* Mp  = (const float*)d_in[4];
    const float* Mm  = (const float*)d_in[5];
    float* out = (float*)d_out;

    char* ws = (char*)d_ws;
    size_t off = 0;
    auto alloc = [&](size_t bytes) { void* p = ws + off; off = (off + bytes + 255) & ~(size_t)255; return p; };
    bf16*  U    = (bf16*) alloc((size_t)ROWS * KT * 2);        // 73.4 MB
    bf16*  BT   = (bf16*) alloc((size_t)512 * KT * 2);         // 18.4 MB
    bf16*  PB   = (bf16*) alloc((size_t)512 * PBLD * 2);       //  3.7 MB
    bf16*  BTT  = (bf16*) alloc((size_t)1024 * 1024 * 2);      //  2.1 MB
    bf16*  Myb  = (bf16*) alloc((size_t)512 * 1024 * 2);       //  1.0 MB
    float* z    = (float*)alloc((size_t)ROWS * D_ * 4);        //  4.2 MB
    bf16*  ZT   = (bf16*) alloc((size_t)ROWS * ZTLD * 2);      // 12.6 MB
    // overlapped region: {W + uPT} dead after conv; partD written after;
    // partD dead after k_ztaps; partR written after.
    char*  region = (char*)alloc((size_t)SPLITD * ROWS * D_ * 4); // 64 MB
    bf16*  W    = (bf16*)region;                               //  6.3 MB (768 tiles)
    bf16*  uPT  = (bf16*)(region + (size_t)768 * 4096 * 2);    //  2.1 MB
    float* partD = (float*)region;
    float* partR = (float*)region;

    // preps (2 launches)
    prep_ew<<<5632, 256, 0, stream>>>(u, fil, Mu, My, U, BT, PB, W, Myb);
    prep_tr<<<dim3(8, 8, 35), 256, 0, stream>>>(Mp, Mm, My, u, BT, BTT, uPT);

    // Stage C (parity-split conv) + phi_misc fused
    conv_misc<<<dim3(4, 4, 131), 256, 0, stream>>>(W, uPT, U, PB, BTT, Myb);

    // Stage D split-K 16 + Phi doubling1 fused (z-slice 16)
    gemm_k<<<dim3(16, 4, SPLITD + 1), 256, 0, stream>>>(U, KT, BT, KT, partD,
                                                        KT / SPLITD, SPLITD, PB, BTT);

    // reduce partials -> z, build shifted taps; + Phi doubling2 fused
    k_ztaps<<<1056, 256, 0, stream>>>(partD, z, ZT, PB, BTT);

    // Stage R: tap-partials = ZT @ [P1..P6]^T, split-K 8
    gemm_k<<<dim3(16, 4, SPLITR), 256, 0, stream>>>(ZT, ZTLD, PB + 512, PBLD,
                                                    partR, ZTLD / SPLITR, -1,
                                                    nullptr, nullptr);

    // out = z + sum partR
    reduce_out<<<(ROWS * D_ / 4 + 255) / 256, 256, 0, stream>>>(z, partR, out);
}

// Round 7
// 259.482 us; speedup vs baseline: 2.0726x; 1.1032x over previous
//
#include <hip/hip_runtime.h>
#include <hip/hip_bf16.h>

// STU forward. R7 = R6 + restructured K-loop:
//  - 3-buffer LDS ring, prefetch-2-deep, raw s_barrier + manual s_waitcnt
//    vmcnt(4) (AITER-style fine-grained drain; per-wave in-order vmcnt).
//  - bf16 split-K partials (halve partD/partR traffic).
//  - fused Phi blocks dispatched FIRST (z=0 / bid<32), conv longest-first.
// Parity-split conv, NTAP=6 explicit-tap AR, 7 launches. bf16 MFMA 16x16x32,
// fp32 acc, XOR swizzle (0 bank conflicts).

using bf16 = __hip_bfloat16;
typedef __attribute__((ext_vector_type(8))) short bf16x8;
typedef __attribute__((ext_vector_type(4))) float f32x4;

#define B_   2
#define L_   1024
#define D_   512
#define K_   16
#define KT   17920      // 32*512 (conv channels) + 3*512 (M_u taps)
#define ROWS 2048       // B*L
#define NTAP 6          // AR taps s=1..6 (s=0 identity in fp32)
#define PBLD 3584       // PB row stride: 7 slots (s=0..6) * 512
#define ZTLD 3072       // ZT row stride: 6 taps * 512
#define SPLITD 16
#define SPLITR 8

// s_waitcnt imm: [3:0] vmcnt lo, [6:4] expcnt, [11:8] lgkmcnt, [15:14] vmcnt hi
#define WAIT_VM4 0x0F74   // vmcnt<=4, exp/lgkm unconstrained
#define WAIT_VM0 0x0F70   // vmcnt<=0

__device__ __forceinline__ void gll16(const void* g, void* l) {
    __builtin_amdgcn_global_load_lds(
        (const __attribute__((address_space(1))) unsigned int*)g,
        (__attribute__((address_space(3))) unsigned int*)l, 16, 0, 0);
}

// ---------------- prep: merged elementwise (vectorized) ----------------
__global__ void prep_ew(const float* __restrict__ u, const float* __restrict__ fil,
                        const float* __restrict__ Mu, const float* __restrict__ My,
                        bf16* __restrict__ U, bf16* __restrict__ BT,
                        bf16* __restrict__ PB, bf16* __restrict__ W,
                        bf16* __restrict__ Myb) {
    int bid = blockIdx.x, tid = threadIdx.x;
    auto pack4 = [](float4 v) {
        ushort4 o; bf16 h;
        h = __float2bfloat16(v.x); o.x = *(unsigned short*)&h;
        h = __float2bfloat16(v.y); o.y = *(unsigned short*)&h;
        h = __float2bfloat16(v.z); o.z = *(unsigned short*)&h;
        h = __float2bfloat16(v.w); o.w = *(unsigned short*)&h;
        return o;
    };
    if (bid < 3072) {                        // U taps
        int e4 = bid * 256 + tid;
        int r = e4 / 384, rem = e4 % 384;
        int t = rem >> 7, f = (rem & 127) * 4;
        int b = r >> 10, l = r & 1023;
        float4 v = {0.f, 0.f, 0.f, 0.f};
        if (l >= t) v = *(const float4*)&u[((size_t)b * L_ + l - t) * D_ + f];
        *(ushort4*)&U[(size_t)r * KT + 16384 + t * 512 + f] = pack4(v);
    } else if (bid < 3840) {                 // BT taps
        int e4 = (bid - 3072) * 256 + tid;
        int o = e4 / 384, tf4 = (e4 % 384) * 4;
        float4 v = *(const float4*)&Mu[(size_t)o * 1536 + tf4];
        *(ushort4*)&BT[(size_t)o * KT + 16384 + tf4] = pack4(v);
    } else if (bid < 4352) {                 // PB: P0=I, P1=M_y[:,0,:]
        int e4 = (bid - 3840) * 256 + tid;
        int n = e4 >> 8, c4 = (e4 & 255) * 4;
        float4 v;
        if (c4 < 512) {
            v.x = (n == c4) ? 1.f : 0.f;     v.y = (n == c4 + 1) ? 1.f : 0.f;
            v.z = (n == c4 + 2) ? 1.f : 0.f; v.w = (n == c4 + 3) ? 1.f : 0.f;
        } else v = *(const float4*)&My[(size_t)n * 1024 + (c4 - 512)];
        *(ushort4*)&PB[(size_t)n * PBLD + c4] = pack4(v);
    } else if (bid < 5120) {                 // Toeplitz W tiles (3 sets), pre-swizzled
        int tile = bid - 4352;
        int set = tile >> 8, rem = tile & 255;
        int k = rem >> 4, g = (rem >> 2) & 3, kb = rem & 3;
        for (int idx = tid; idx < 4096; idx += 256) {
            int i = idx >> 5, jp = idx & 31;
            int j = ((jp >> 3) ^ ((i >> 1) & 3)) * 8 + (jp & 7);
            int x = g * 128 + i - kb * 32 - j - (set == 2 ? 1 : 0);
            float v = 0.f;
            if (x >= 0) {
                int row = (set == 0) ? 2 * x : 2 * x + 1;
                v = fil[row * K_ + k];
            }
            W[(size_t)tile * 4096 + idx] = __float2bfloat16(v);
        }
    } else {                                 // Myb = bf16(My)
        int e4 = (bid - 5120) * 256 + tid;
        float4 v = *(const float4*)&My[(size_t)e4 * 4];
        *(ushort4*)&Myb[(size_t)e4 * 4] = pack4(v);
    }
}

// ---------------- prep: merged transposes ----------------
__global__ void prep_tr(const float* __restrict__ Mp, const float* __restrict__ Mm,
                        const float* __restrict__ My, const float* __restrict__ u,
                        bf16* __restrict__ BT, bf16* __restrict__ BTT,
                        bf16* __restrict__ uPT) {
    __shared__ bf16 t[64][72];
    int zb = blockIdx.z;
    int col = threadIdx.x & 63, r0 = (threadIdx.x >> 6) * 16;
    if (zb < 32) {                           // BT[o][c*512+d] = (Mp +/- Mm)[k][d][o]
        int dt = blockIdx.x * 64, ot = blockIdx.y * 64, c = zb;
        int k = c & 15;
        const float* sp = Mp + (size_t)k * D_ * D_;
        const float* sm = Mm + (size_t)k * D_ * D_;
        float sg = (c < 16) ? 1.f : -1.f;
        for (int i = 0; i < 16; ++i) {
            size_t o_ = (size_t)(dt + r0 + i) * D_ + ot + col;
            t[r0 + i][col] = __float2bfloat16(sp[o_] + sg * sm[o_]);
        }
        __syncthreads();
        for (int i = 0; i < 16; ++i)
            BT[(size_t)(ot + r0 + i) * KT + c * D_ + dt + col] = t[col][r0 + i];
    } else if (zb < 34) {                    // BTT[f][h*512+d] = M_y[d][1-h][f]
        int h = zb - 32;
        int dt = blockIdx.x * 64, ft = blockIdx.y * 64;
        for (int i = 0; i < 16; ++i)
            t[r0 + i][col] = __float2bfloat16(My[(size_t)(dt + r0 + i) * 1024 + (1 - h) * 512 + ft + col]);
        __syncthreads();
        for (int i = 0; i < 16; ++i)
            BTT[(size_t)(ft + r0 + i) * 1024 + h * 512 + dt + col] = t[col][r0 + i];
    } else {                                 // uPT[b][p][d][m'] = u[b][2m'+p][d]
        for (int it = 0; it < 4; ++it) {
            int b = it >> 1, p = it & 1;
            int mt = blockIdx.x * 64, dt = blockIdx.y * 64;
            __syncthreads();
            for (int i = 0; i < 16; ++i)
                t[r0 + i][col] = __float2bfloat16(u[((size_t)b * L_ + 2 * (mt + r0 + i) + p) * D_ + dt + col]);
            __syncthreads();
            for (int i = 0; i < 16; ++i)
                uPT[((size_t)it * 512 + dt + r0 + i) * 512 + mt + col] = t[col][r0 + i];
        }
    }
}

// ---- shared body for small bf16-out GEMMs (caller LDS, __syncthreads ok) ----
__device__ __forceinline__ void phi_body(
    const bf16* A, int lda, const bf16* BT, int ldb,
    bf16* out, int ldo, int klen, const bf16* add, int lad,
    int row0, int col0, bf16* sA, bf16* sB)
{
    const int tid = threadIdx.x, lane = tid & 63, wave = tid >> 6;
    const int wm = (wave & 1) * 64, wn = (wave >> 1) * 64;
    const int ml = lane & 15, q = lane >> 4;
    const int srow = lane >> 2, scol = (((lane & 3) ^ ((srow >> 1) & 3))) * 8;
    const int swz = ((ml >> 1) & 3);
    f32x4 acc[4][4] = {};

    for (int k = 0; k < klen; k += 32) {
        __syncthreads();
        #pragma unroll
        for (int repi = 0; repi < 2; ++repi) {
            int a = wave + repi * 4;
            gll16(A  + (size_t)(row0 + a * 16 + srow) * lda + k + scol, &sA[a * 512]);
            gll16(BT + (size_t)(col0 + a * 16 + srow) * ldb + k + scol, &sB[a * 512]);
        }
        __syncthreads();
        bf16x8 af[4], bfr[4];
        #pragma unroll
        for (int i = 0; i < 4; ++i)
            af[i] = *(const bf16x8*)&sA[(wm + i * 16 + ml) * 32 + (q ^ swz) * 8];
        #pragma unroll
        for (int j = 0; j < 4; ++j)
            bfr[j] = *(const bf16x8*)&sB[(wn + j * 16 + ml) * 32 + (q ^ swz) * 8];
        #pragma unroll
        for (int i = 0; i < 4; ++i)
            #pragma unroll
            for (int j = 0; j < 4; ++j)
                acc[i][j] = __builtin_amdgcn_mfma_f32_16x16x32_bf16(af[i], bfr[j], acc[i][j], 0, 0, 0);
    }
    #pragma unroll
    for (int i = 0; i < 4; ++i)
        #pragma unroll
        for (int j = 0; j < 4; ++j)
            #pragma unroll
            for (int reg = 0; reg < 4; ++reg) {
                int r = row0 + wm + i * 16 + q * 4 + reg;
                int cc = col0 + wn + j * 16 + ml;
                float v = acc[i][j][reg];
                if (add) v += __bfloat162float(add[(size_t)r * lad + cc]);
                out[(size_t)r * ldo + cc] = __float2bfloat16(v);
            }
}

// sum 16 bf16 Stage-D partials -> z (fp32) + shifted bf16 taps ZT
// bid<32: fused Phi doubling2 [P5|P6] = [P3|P4] x BTT (dispatched FIRST)
__global__ void k_ztaps(const bf16* __restrict__ partD, float* __restrict__ z,
                        bf16* __restrict__ ZT, bf16* PB, const bf16* BTT) {
    __shared__ bf16 sA[4096];
    __shared__ bf16 sB[4096];
    int bid = blockIdx.x;
    if (bid < 32) {
        int row0 = (bid & 3) * 128, col0 = (bid >> 2) * 128;
        phi_body(PB + 3 * 512, PBLD, BTT, 1024, PB + 5 * 512, PBLD, 1024,
                 nullptr, 0, row0, col0, sA, sB);
        return;
    }
    int t = (bid - 32) * 256 + threadIdx.x;  // ROWS*D_/4 threads exactly
    int r = t >> 7, f4 = (t & 127) * 4;
    const ushort4* p = (const ushort4*)partD;
    float4 s = {0.f, 0.f, 0.f, 0.f};
    #pragma unroll
    for (int c = 0; c < SPLITD; ++c) {
        ushort4 v = p[(size_t)c * (ROWS * D_ / 4) + t];
        s.x += __uint_as_float((unsigned)v.x << 16);
        s.y += __uint_as_float((unsigned)v.y << 16);
        s.z += __uint_as_float((unsigned)v.z << 16);
        s.w += __uint_as_float((unsigned)v.w << 16);
    }
    ((float4*)z)[t] = s;
    ushort4 zb;
    { bf16 h;
      h = __float2bfloat16(s.x); zb.x = *(unsigned short*)&h;
      h = __float2bfloat16(s.y); zb.y = *(unsigned short*)&h;
      h = __float2bfloat16(s.z); zb.z = *(unsigned short*)&h;
      h = __float2bfloat16(s.w); zb.w = *(unsigned short*)&h; }
    int l = r & 1023;
    #pragma unroll
    for (int sh = 1; sh <= NTAP; ++sh)
        if (l + sh < 1024)
            *(ushort4*)&ZT[(size_t)(r + sh) * ZTLD + (sh - 1) * 512 + f4] = zb;
    ushort4 z4 = {0, 0, 0, 0};
    for (int sh = l + 1; sh <= NTAP; ++sh)
        *(ushort4*)&ZT[(size_t)r * ZTLD + (sh - 1) * 512 + f4] = z4;
}

// out = z + sum of SPLITR bf16 Stage-R partials
__global__ void reduce_out(const float* __restrict__ z, const bf16* __restrict__ partR,
                           float* __restrict__ out) {
    int t = blockIdx.x * 256 + threadIdx.x;
    if (t >= ROWS * D_ / 4) return;
    float4 s = ((const float4*)z)[t];
    const ushort4* p = (const ushort4*)partR;
    #pragma unroll
    for (int c = 0; c < SPLITR; ++c) {
        ushort4 v = p[(size_t)c * (ROWS * D_ / 4) + t];
        s.x += __uint_as_float((unsigned)v.x << 16);
        s.y += __uint_as_float((unsigned)v.y << 16);
        s.z += __uint_as_float((unsigned)v.z << 16);
        s.w += __uint_as_float((unsigned)v.w << 16);
    }
    ((float4*)out)[t] = s;
}

// ---------------- Stage C: parity-split conv, 3-buf pipelined ----------------
// grid (4,4,131). z=0..2: phi_misc {P2,X1,X2} (dispatched first).
// z>=3: zc=z-3; t=zc&3, b=(zc>>2)&1, k=zc>>3; mt = 3-blockIdx.x (longest first).
__global__ __launch_bounds__(256, 3) void conv_misc(
    const bf16* __restrict__ W, const bf16* __restrict__ uPT,
    bf16* __restrict__ U,
    const bf16* PB, const bf16* BTT, const bf16* Myb)
{
    __shared__ bf16 sA[3][4096];
    __shared__ bf16 sB[3][4096];
    const int z = blockIdx.z;
    if (z < 3) {
        int row0 = blockIdx.x * 128, col0 = blockIdx.y * 128;
        bf16* BTTw = (bf16*)BTT; bf16* PBw = (bf16*)PB;
        if (z == 0)
            phi_body(PB, PBLD, BTT, 1024, PBw + 2 * 512, PBLD, 1024,
                     nullptr, 0, row0, col0, &sA[0][0], &sB[0][0]);
        else if (z == 1)
            phi_body(BTT + 512, 1024, Myb + 512, 1024,
                     BTTw + (size_t)512 * 1024, 1024, 512,
                     nullptr, 0, row0, col0, &sA[0][0], &sB[0][0]);
        else
            phi_body(BTT + 512, 1024, Myb, 1024,
                     BTTw + (size_t)512 * 1024 + 512, 1024, 512,
                     BTT, 1024, row0, col0, &sA[0][0], &sB[0][0]);
        return;
    }
    const int zc = z - 3;
    const int mt = 3 - blockIdx.x, dt = blockIdx.y * 128;
    const int t = zc & 3, b = (zc >> 2) & 1, k = zc >> 3;
    const int pb_ = t & 1;
    const int p = (t & 1) ^ (t >> 1);
    const int set = (t < 2) ? 0 : (t == 2 ? 1 : 2);
    const int ch = (t < 2) ? k : 16 + k;
    const int plane = b * 2 + pb_;
    const int tid = threadIdx.x, lane = tid & 63, wave = tid >> 6;
    const int wm = (wave & 1) * 64, wn = (wave >> 1) * 64;
    const int ml = lane & 15, q = lane >> 4;
    const int srow = lane >> 2, scol = (((lane & 3) ^ ((srow >> 1) & 3))) * 8;
    const int swz = ((ml >> 1) & 3);
    f32x4 acc[4][4] = {};
    const int n = (mt + 1) * 4;              // 32-K steps

    const bf16* bB0 = uPT + ((size_t)plane * 512 + dt + wave * 16       + srow) * 512 + scol;
    const bf16* bB1 = uPT + ((size_t)plane * 512 + dt + (wave + 4) * 16 + srow) * 512 + scol;
    const bf16* wbase = W + ((size_t)(set * 16 + k) * 16) * 4096;
    auto stage = [&](int s, int buf) {
        const bf16* wt = wbase + ((size_t)((mt - (s >> 2)) * 4 + (s & 3))) * 4096;
        gll16(wt + wave * 512 + lane * 8, &sA[buf][wave * 512]);
        gll16(wt + (wave + 4) * 512 + lane * 8, &sA[buf][(wave + 4) * 512]);
        gll16(bB0 + s * 32, &sB[buf][wave * 512]);
        gll16(bB1 + s * 32, &sB[buf][(wave + 4) * 512]);
    };
    auto compute = [&](int c) {
        bf16x8 af[4], bfr[4];
        #pragma unroll
        for (int i = 0; i < 4; ++i)
            af[i] = *(const bf16x8*)&sA[c][(wm + i * 16 + ml) * 32 + (q ^ swz) * 8];
        #pragma unroll
        for (int j = 0; j < 4; ++j)
            bfr[j] = *(const bf16x8*)&sB[c][(wn + j * 16 + ml) * 32 + (q ^ swz) * 8];
        #pragma unroll
        for (int i = 0; i < 4; ++i)
            #pragma unroll
            for (int j = 0; j < 4; ++j)
                acc[i][j] = __builtin_amdgcn_mfma_f32_16x16x32_bf16(af[i], bfr[j], acc[i][j], 0, 0, 0);
    };
    stage(0, 0); stage(1, 1);
    int c = 0, nb = 2;
    for (int i = 0; i < n - 1; ++i) {
        __builtin_amdgcn_s_waitcnt(WAIT_VM4);   // oldest stage landed (all 4 loads)
        __builtin_amdgcn_s_barrier();
        if (i + 2 < n) stage(i + 2, nb);
        compute(c);
        c = (c == 2) ? 0 : c + 1; nb = (nb == 2) ? 0 : nb + 1;
    }
    __builtin_amdgcn_s_waitcnt(WAIT_VM0);
    __builtin_amdgcn_s_barrier();
    compute(c);

    #pragma unroll
    for (int i = 0; i < 4; ++i)
        #pragma unroll
        for (int j = 0; j < 4; ++j)
            #pragma unroll
            for (int reg = 0; reg < 4; ++reg) {
                int m = mt * 128 + wm + i * 16 + q * 4 + reg;
                int l = 2 * m + p;
                int d = dt + wn + j * 16 + ml;
                U[(size_t)(b * L_ + l) * KT + ch * 512 + d] = __float2bfloat16(acc[i][j][reg]);
            }
}

// ------- split-K partial GEMM, 3-buf pipelined (+ optional doubling z=0) -----
__global__ __launch_bounds__(256, 3) void gemm_k(
    const bf16* __restrict__ A, int lda,
    const bf16* __restrict__ BT, int ldb,
    bf16* __restrict__ part, int k_chunk, int zoff,
    const bf16* PB, const bf16* BTT)
{
    __shared__ bf16 sA[3][4096];
    __shared__ bf16 sB[3][4096];
    if (zoff && blockIdx.z == 0) {            // doubling1: [P3|P4] = [P1|P2] x BTT
        int x = blockIdx.x;
        if (x >= 8) return;
        int row0 = (x & 3) * 128;
        int col0 = (((x >> 2) * 4) + blockIdx.y) * 128;
        phi_body(PB + 512, PBLD, BTT, 1024, (bf16*)PB + 3 * 512, PBLD, 1024,
                 nullptr, 0, row0, col0, &sA[0][0], &sB[0][0]);
        return;
    }
    const int zz = blockIdx.z - zoff;
    const int row0 = blockIdx.x * 128, col0 = blockIdx.y * 128;
    const int k0 = zz * k_chunk;
    const int n = k_chunk >> 5;
    const int tid = threadIdx.x, lane = tid & 63, wave = tid >> 6;
    const int wm = (wave & 1) * 64, wn = (wave >> 1) * 64;
    const int ml = lane & 15, q = lane >> 4;
    const int srow = lane >> 2, scol = (((lane & 3) ^ ((srow >> 1) & 3))) * 8;
    const int swz = ((ml >> 1) & 3);
    f32x4 acc[4][4] = {};

    const bf16* bA0 = A  + (size_t)(row0 + wave * 16       + srow) * lda + k0 + scol;
    const bf16* bA1 = A  + (size_t)(row0 + (wave + 4) * 16 + srow) * lda + k0 + scol;
    const bf16* bB0 = BT + (size_t)(col0 + wave * 16       + srow) * ldb + k0 + scol;
    const bf16* bB1 = BT + (size_t)(col0 + (wave + 4) * 16 + srow) * ldb + k0 + scol;
    auto stage = [&](int s, int buf) {
        gll16(bA0 + s * 32, &sA[buf][wave * 512]);
        gll16(bA1 + s * 32, &sA[buf][(wave + 4) * 512]);
        gll16(bB0 + s * 32, &sB[buf][wave * 512]);
        gll16(bB1 + s * 32, &sB[buf][(wave + 4) * 512]);
    };
    auto compute = [&](int c) {
        bf16x8 af[4], bfr[4];
        #pragma unroll
        for (int i = 0; i < 4; ++i)
            af[i] = *(const bf16x8*)&sA[c][(wm + i * 16 + ml) * 32 + (q ^ swz) * 8];
        #pragma unroll
        for (int j = 0; j < 4; ++j)
            bfr[j] = *(const bf16x8*)&sB[c][(wn + j * 16 + ml) * 32 + (q ^ swz) * 8];
        #pragma unroll
        for (int i = 0; i < 4; ++i)
            #pragma unroll
            for (int j = 0; j < 4; ++j)
                acc[i][j] = __builtin_amdgcn_mfma_f32_16x16x32_bf16(af[i], bfr[j], acc[i][j], 0, 0, 0);
    };
    stage(0, 0); stage(1, 1);
    int c = 0, nb = 2;
    for (int i = 0; i < n - 1; ++i) {
        __builtin_amdgcn_s_waitcnt(WAIT_VM4);
        __builtin_amdgcn_s_barrier();
        if (i + 2 < n) stage(i + 2, nb);
        compute(c);
        c = (c == 2) ? 0 : c + 1; nb = (nb == 2) ? 0 : nb + 1;
    }
    __builtin_amdgcn_s_waitcnt(WAIT_VM0);
    __builtin_amdgcn_s_barrier();
    compute(c);

    bf16* o = part + (size_t)zz * ROWS * D_;
    #pragma unroll
    for (int i = 0; i < 4; ++i)
        #pragma unroll
        for (int j = 0; j < 4; ++j)
            #pragma unroll
            for (int reg = 0; reg < 4; ++reg) {
                int r = row0 + wm + i * 16 + q * 4 + reg;
                int cc = col0 + wn + j * 16 + ml;
                o[(size_t)r * D_ + cc] = __float2bfloat16(acc[i][j][reg]);
            }
}

// ---------------- launch ----------------
extern "C" void kernel_launch(void* const* d_in, const int* in_sizes, int n_in,
                              void* d_out, int out_size, void* d_ws, size_t ws_size,
                              hipStream_t stream) {
    const float* u   = (const float*)d_in[0];
    const float* fil = (const float*)d_in[1];
    const float* Mu  = (const float*)d_in[2];
    const float* My  = (const float*)d_in[3];
    const float* Mp  = (const float*)d_in[4];
    const float* Mm  = (const float*)d_in[5];
    float* out = (float*)d_out;

    char* ws = (char*)d_ws;
    size_t off = 0;
    auto alloc = [&](size_t bytes) { void* p = ws + off; off = (off + bytes + 255) & ~(size_t)255; return p; };
    bf16*  U    = (bf16*) alloc((size_t)ROWS * KT * 2);        // 73.4 MB
    bf16*  BT   = (bf16*) alloc((size_t)512 * KT * 2);         // 18.4 MB
    bf16*  PB   = (bf16*) alloc((size_t)512 * PBLD * 2);       //  3.7 MB
    bf16*  BTT  = (bf16*) alloc((size_t)1024 * 1024 * 2);      //  2.1 MB
    bf16*  Myb  = (bf16*) alloc((size_t)512 * 1024 * 2);       //  1.0 MB
    float* z    = (float*)alloc((size_t)ROWS * D_ * 4);        //  4.2 MB
    bf16*  ZT   = (bf16*) alloc((size_t)ROWS * ZTLD * 2);      // 12.6 MB
    // overlapped region: {W + uPT} dead after conv; bf16 partD written after;
    // partD dead after k_ztaps; bf16 partR written after.
    char*  region = (char*)alloc((size_t)SPLITD * ROWS * D_ * 2); // 32 MB
    bf16*  W    = (bf16*)region;                               //  6.3 MB (768 tiles)
    bf16*  uPT  = (bf16*)(region + (size_t)768 * 4096 * 2);    //  2.1 MB
    bf16*  partD = (bf16*)region;
    bf16*  partR = (bf16*)region;

    // preps (2 launches)
    prep_ew<<<5632, 256, 0, stream>>>(u, fil, Mu, My, U, BT, PB, W, Myb);
    prep_tr<<<dim3(8, 8, 35), 256, 0, stream>>>(Mp, Mm, My, u, BT, BTT, uPT);

    // Stage C (parity-split conv, pipelined) + phi_misc fused (z=0..2, first)
    conv_misc<<<dim3(4, 4, 131), 256, 0, stream>>>(W, uPT, U, PB, BTT, Myb);

    // Stage D split-K 16 (pipelined) + Phi doubling1 fused at z=0
    gemm_k<<<dim3(16, 4, SPLITD + 1), 256, 0, stream>>>(U, KT, BT, KT, partD,
                                                        KT / SPLITD, 1, PB, BTT);

    // reduce partials -> z + taps; Phi doubling2 fused at bid<32 (first)
    k_ztaps<<<1056, 256, 0, stream>>>(partD, z, ZT, PB, BTT);

    // Stage R: tap-partials = ZT @ [P1..P6]^T, split-K 8 (pipelined)
    gemm_k<<<dim3(16, 4, SPLITR), 256, 0, stream>>>(ZT, ZTLD, PB + 512, PBLD,
                                                    partR, ZTLD / SPLITR, 0,
                                                    nullptr, nullptr);

    // out = z + sum partR
    reduce_out<<<(ROWS * D_ / 4 + 255) / 256, 256, 0, stream>>>(z, partR, out);
}